// Round 3
// baseline (31008.395 us; speedup 1.0000x reference)
//
#include <hip/hip_runtime.h>
#include <hip/hip_bf16.h>
#include <math.h>

typedef __hip_bfloat16 bf16;

#define B_ 16
#define L_ 1000
#define D_ 512
#define H_ 8
#define N_ 1024
#define FF_ 2048
#define DEPTH_ 6
#define PAD_ 24
#define SCALE_ 0.125f

__device__ inline float toF(float x){ return x; }
__device__ inline float toF(bf16 x){ return __bfloat162float(x); }
__device__ inline void stv(float* p, float v){ *p = v; }
__device__ inline void stv(bf16* p, float v){ *p = __float2bfloat16(v); }

// ---------- block reductions (256 threads = 4 waves of 64) ----------
__device__ inline float blockSum256(float v, float* red){
  int t = threadIdx.x;
  #pragma unroll
  for (int o = 32; o > 0; o >>= 1) v += __shfl_down(v, o, 64);
  __syncthreads();
  if ((t & 63) == 0) red[t >> 6] = v;
  __syncthreads();
  return red[0] + red[1] + red[2] + red[3];
}
__device__ inline float blockMax256(float v, float* red){
  int t = threadIdx.x;
  #pragma unroll
  for (int o = 32; o > 0; o >>= 1) v = fmaxf(v, __shfl_down(v, o, 64));
  __syncthreads();
  if ((t & 63) == 0) red[t >> 6] = v;
  __syncthreads();
  return fmaxf(fmaxf(red[0], red[1]), fmaxf(red[2], red[3]));
}

// ---------- embedding (f32 inputs) ----------
__global__ __launch_bounds__(256) void embed_kernel(
    const int* __restrict__ x, const float* __restrict__ ee,
    const float* __restrict__ pe, float* __restrict__ h)
{
  long long i = (long long)blockIdx.x * 256 + threadIdx.x;  // 16*1000*512
  int d = (int)(i & 511);
  long long bl = i >> 9;
  int l = (int)(bl % 1000);
  int tok = x[bl];
  h[i] = ee[tok * D_ + d] + pe[l * D_ + d];
}

// ---------- layernorm: f32 in -> bf16 out. pad=1: (b,1024) rows, first 24 zero
__global__ __launch_bounds__(256) void ln_kernel(
    const float* __restrict__ in, bf16* __restrict__ out,
    const float* __restrict__ sc, const float* __restrict__ bi, int pad)
{
  __shared__ float red[4];
  int r = blockIdx.x, t = threadIdx.x;
  const float* row; bf16* orow;
  if (pad){
    int bb = r >> 10, n = r & 1023;
    orow = out + (long long)r * D_;
    if (n < PAD_){ orow[t] = __float2bfloat16(0.f); orow[t + 256] = __float2bfloat16(0.f); return; }
    row = in + ((long long)bb * L_ + (n - PAD_)) * D_;
  } else {
    row  = in  + (long long)r * D_;
    orow = out + (long long)r * D_;
  }
  float x0 = row[t], x1 = row[t + 256];
  float mu = blockSum256(x0 + x1, red) * (1.f / 512.f);
  float d0 = x0 - mu, d1 = x1 - mu;
  float var = blockSum256(d0 * d0 + d1 * d1, red) * (1.f / 512.f);
  float rs = rsqrtf(var + 1e-5f);
  orow[t]       = __float2bfloat16(d0 * rs * sc[t]       + bi[t]);
  orow[t + 256] = __float2bfloat16(d1 * rs * sc[t + 256] + bi[t + 256]);
}

// ---------- generic tiled GEMM: C = scale*(alpha*A[i,j] - A@B) (+bias,gelu,acc)
// plain C=A@B -> scale=-1, alpha=0. flags: 1=accumulate into C, 2=exact gelu.
template<typename TA, typename TB, typename TC>
__global__ __launch_bounds__(256) void gemm_kernel(
    const TA* __restrict__ Ab, const TB* __restrict__ Bb, TC* __restrict__ Cb,
    const float* __restrict__ bias,
    int M, int N, int K, int lda, int ldb, int ldc,
    long long sAb, long long sAh, long long sBb, long long sBh,
    long long sCb, long long sCh, int nh,
    float scale, float alpha, int flags)
{
  __shared__ float As[16][68];
  __shared__ float Bs[16][68];
  int bz = blockIdx.z;
  int b = bz / nh, hh = bz - b * nh;
  const TA* A  = Ab + (long long)b * sAb + (long long)hh * sAh;
  const TB* Bm = Bb + (long long)b * sBb + (long long)hh * sBh;
  TC*       C  = Cb + (long long)b * sCb + (long long)hh * sCh;
  const int m0 = blockIdx.y << 6, n0 = blockIdx.x << 6;
  const int t = threadIdx.x;
  const int tx = t & 15, ty = t >> 4;
  const int a_m = t >> 2, a_k = (t & 3) << 2;   // A tile: 64 rows x 16 k
  const int b_k = t >> 4, b_n = (t & 15) << 2;  // B tile: 16 k x 64 cols
  float acc[4][4] = {};
  for (int k0 = 0; k0 < K; k0 += 16){
    int arow = m0 + a_m;
    float a0 = 0.f, a1 = 0.f, a2 = 0.f, a3 = 0.f;
    if (arow < M){
      const TA* ap = A + (long long)arow * lda + k0 + a_k;
      a0 = toF(ap[0]); a1 = toF(ap[1]); a2 = toF(ap[2]); a3 = toF(ap[3]);
    }
    As[a_k + 0][a_m] = a0; As[a_k + 1][a_m] = a1;
    As[a_k + 2][a_m] = a2; As[a_k + 3][a_m] = a3;
    {
      float b0 = 0.f, b1 = 0.f, b2 = 0.f, b3 = 0.f;
      if (n0 + b_n < N){
        const TB* bp = Bm + (long long)(k0 + b_k) * ldb + n0 + b_n;
        b0 = toF(bp[0]); b1 = toF(bp[1]); b2 = toF(bp[2]); b3 = toF(bp[3]);
      }
      Bs[b_k][b_n + 0] = b0; Bs[b_k][b_n + 1] = b1;
      Bs[b_k][b_n + 2] = b2; Bs[b_k][b_n + 3] = b3;
    }
    __syncthreads();
    #pragma unroll
    for (int kk = 0; kk < 16; kk++){
      float4 a4 = *(const float4*)(&As[kk][ty << 2]);
      float4 b4 = *(const float4*)(&Bs[kk][tx << 2]);
      acc[0][0] += a4.x * b4.x; acc[0][1] += a4.x * b4.y;
      acc[0][2] += a4.x * b4.z; acc[0][3] += a4.x * b4.w;
      acc[1][0] += a4.y * b4.x; acc[1][1] += a4.y * b4.y;
      acc[1][2] += a4.y * b4.z; acc[1][3] += a4.y * b4.w;
      acc[2][0] += a4.z * b4.x; acc[2][1] += a4.z * b4.y;
      acc[2][2] += a4.z * b4.z; acc[2][3] += a4.z * b4.w;
      acc[3][0] += a4.w * b4.x; acc[3][1] += a4.w * b4.y;
      acc[3][2] += a4.w * b4.z; acc[3][3] += a4.w * b4.w;
    }
    __syncthreads();
  }
  #pragma unroll
  for (int i = 0; i < 4; i++){
    int row = m0 + (ty << 2) + i;
    if (row >= M) continue;
    #pragma unroll
    for (int j = 0; j < 4; j++){
      int col = n0 + (tx << 2) + j;
      if (col >= N) continue;
      float v = acc[i][j];
      float at = (alpha != 0.f) ? toF(A[(long long)row * lda + col]) : 0.f;
      v = scale * (alpha * at - v);
      if (bias) v += bias[col];
      if (flags & 2) v = 0.5f * v * (1.f + erff(v * 0.7071067811865476f));
      TC* cp = C + (long long)row * ldc + col;
      if (flags & 1) v += toF(*cp);
      stv(cp, v);
    }
  }
}

// ---------- row softmax, row length = PER*256, in place ----------
template<int PER, typename T>
__global__ __launch_bounds__(256) void softmax_kernel(T* __restrict__ d)
{
  __shared__ float red[4];
  long long r = blockIdx.x;
  T* row = d + r * (PER * 256);
  int t = threadIdx.x;
  float vals[PER];
  float mx = -3.4e38f;
  #pragma unroll
  for (int i = 0; i < PER; i++){ vals[i] = toF(row[t + i * 256]); mx = fmaxf(mx, vals[i]); }
  mx = blockMax256(mx, red);
  float s = 0.f;
  #pragma unroll
  for (int i = 0; i < PER; i++){ vals[i] = expf(vals[i] - mx); s += vals[i]; }
  s = blockSum256(s, red);
  float inv = 1.f / s;
  #pragma unroll
  for (int i = 0; i < PER; i++) stv(&row[t + i * 256], vals[i] * inv);
}

// ---------- landmarks: ql (scaled, bf16), klT (transposed, bf16) ----------
__global__ __launch_bounds__(256) void landmark_kernel(
    const bf16* __restrict__ qkv, bf16* __restrict__ ql, bf16* __restrict__ klT)
{
  long long i = (long long)blockIdx.x * 256 + threadIdx.x;  // 128*256*64
  int d = (int)(i & 63);
  long long r = i >> 6;
  int m = (int)(r & 255);
  int bh = (int)(r >> 8);
  int hh = bh & 7, b = bh >> 3;
  const bf16* base = qkv + ((long long)b * N_ + m * 4) * 1536 + hh * 64 + d;
  float qs = toF(base[0]) + toF(base[1536]) + toF(base[3072]) + toF(base[4608]);
  float ks = toF(base[512]) + toF(base[2048]) + toF(base[3584]) + toF(base[5120]);
  ql[i] = __float2bfloat16(qs * 0.25f * SCALE_);
  klT[(long long)bh * 16384 + d * 256 + m] = __float2bfloat16(ks * 0.25f);
}

// ---------- k transpose: kT[bh, d, n] = k[b, n, h, d] (bf16 copy) ----------
__global__ __launch_bounds__(256) void ktrans_kernel(
    const bf16* __restrict__ qkv, bf16* __restrict__ kT)
{
  long long i = (long long)blockIdx.x * 256 + threadIdx.x;  // 128*64*1024
  int n = (int)(i & 1023);
  long long r = i >> 10;
  int d = (int)(r & 63);
  int bh = (int)(r >> 6);
  int hh = bh & 7, b = bh >> 3;
  kT[i] = qkv[((long long)b * N_ + n) * 1536 + 512 + hh * 64 + d];
}

// ---------- pinv scale helpers (f32 attn2) ----------
__global__ void zero_kernel(float* p, int n){
  int i = blockIdx.x * 64 + threadIdx.x;
  if (i < n) p[i] = 0.f;
}
__global__ __launch_bounds__(256) void rcmax_kernel(
    const float* __restrict__ x, float* __restrict__ scal)
{
  __shared__ float red[4];
  int bh = blockIdx.x, t = threadIdx.x;
  const float* X = x + (long long)bh * 65536;
  float cs = 0.f, rs = 0.f;
  for (int m = 0; m < 256; m++) cs += fabsf(X[m * 256 + t]);
  for (int j = 0; j < 256; j++) rs += fabsf(X[t * 256 + j]);
  float cmax = blockMax256(cs, red);
  float rmax = blockMax256(rs, red);
  if (t == 0){
    atomicMax((unsigned int*)(scal + 0), __float_as_uint(rmax));
    atomicMax((unsigned int*)(scal + 1), __float_as_uint(cmax));
  }
}
// z = x^T * inv  (per 32-bh chunk; grid 8192)
__global__ __launch_bounds__(256) void zinit_kernel(
    const float* __restrict__ x, float* __restrict__ z, const float* __restrict__ scal)
{
  float inv = 1.f / (scal[0] * scal[1]);
  long long i = (long long)blockIdx.x * 256 + threadIdx.x;  // 32*65536
  long long bh = i >> 16;
  int ij = (int)(i & 65535);
  int ii = ij >> 8, jj = ij & 255;
  z[(bh << 16) + (ii << 8) + jj] = x[(bh << 16) + (jj << 8) + ii] * inv;
}

// ---------- depthwise conv (k=33, zero pad 16), accumulate into apre ----------
__global__ __launch_bounds__(256) void conv_kernel(
    const bf16* __restrict__ qkv, const float* __restrict__ ck, float* __restrict__ out)
{
  long long i = (long long)blockIdx.x * 256 + threadIdx.x;  // 16*1024*512
  int c = (int)(i & 511);
  long long r = i >> 9;
  int n = (int)(r & 1023);
  int b = (int)(r >> 10);
  int hh = c >> 6;
  const float* kk = ck + hh * 33;
  float acc = 0.f;
  #pragma unroll
  for (int t = 0; t < 33; t++){
    int nn = n + t - 16;
    if (nn >= 0 && nn < N_)
      acc += toF(qkv[((long long)b * N_ + nn) * 1536 + 1024 + c]) * kk[t];
  }
  out[i] += acc;
}

// ---------- final: out[b] = h[b,:] . final_w + final_b ----------
__global__ __launch_bounds__(256) void final_kernel(
    const float* __restrict__ h, const float* __restrict__ w,
    const float* __restrict__ bb, float* __restrict__ out)
{
  __shared__ float red[4];
  int b = blockIdx.x, t = threadIdx.x;
  const float* hp = h + (long long)b * (L_ * D_);
  float acc = 0.f;
  for (int i = t; i < L_ * D_; i += 256) acc += hp[i] * w[i];
  acc = blockSum256(acc, red);
  if (t == 0) out[b] = acc + bb[0];
}

// ---------- host-side GEMM wrapper ----------
template<typename TA, typename TB, typename TC>
static inline void run_gemm(hipStream_t st, const TA* A, const TB* B, TC* C,
  const float* bias, int M, int N, int K, int lda, int ldb, int ldc,
  long long sAb, long long sAh, long long sBb, long long sBh,
  long long sCb, long long sCh, int batch, int nh,
  float scale, float alpha, int flags)
{
  dim3 g((N + 63) >> 6, (M + 63) >> 6, batch);
  gemm_kernel<TA, TB, TC><<<g, 256, 0, st>>>(A, B, C, bias, M, N, K, lda, ldb, ldc,
      sAb, sAh, sBb, sBh, sCb, sCh, nh, scale, alpha, flags);
}

extern "C" void kernel_launch(void* const* d_in, const int* in_sizes, int n_in,
                              void* d_out, int out_size, void* d_ws, size_t ws_size,
                              hipStream_t stream)
{
  const int*   xin  = (const int*)d_in[0];
  const float* enc  = (const float*)d_in[1];
  const float* pos  = (const float*)d_in[2];
  const float* ln1s = (const float*)d_in[3];
  const float* ln1b = (const float*)d_in[4];
  const float* qkvw = (const float*)d_in[5];
  const float* ow   = (const float*)d_in[6];
  const float* ob   = (const float*)d_in[7];
  const float* ck   = (const float*)d_in[8];
  const float* ln2s = (const float*)d_in[9];
  const float* ln2b = (const float*)d_in[10];
  const float* w1   = (const float*)d_in[11];
  const float* b1   = (const float*)d_in[12];
  const float* w2   = (const float*)d_in[13];
  const float* b2   = (const float*)d_in[14];
  const float* fw   = (const float*)d_in[15];
  const float* fb   = (const float*)d_in[16];
  float* out = (float*)d_out;

  // ---- workspace layout: ~242.5 MB total. f32 region, then bf16 region ----
  const size_t NEED = 242483264ULL;
  if (ws_size < NEED) return;   // diagnostic gate: clean absmax-fail => ws too small

  float* F = (float*)d_ws;
  float* h    = F; F += 8192000;            // (16,1000,512) residual stream
  float* xat  = F; F += 8388608;            // attn2 probs (bh,256,256); later attn1-prob chunks
  float* preg = F; F += 8388608;            // attn3-prob chunk / apre / FF chunk
  float* pz0  = F; F += 2097152;            // pinv rotation buffers (32-bh chunk)
  float* pz1  = F; F += 2097152;
  float* pz2  = F; F += 2097152;
  float* pz3  = F; F += 2097152;
  float* a3v  = F; F += 2097152;            // (bh,256,64)
  float* Wl   = F; F += 2097152;            // (bh,256,64)
  float* scal = F; F += 16;
  bf16* G = (bf16*)F;
  bf16* xln = G; G += 8388608;              // LN1 padded (16,1024,512) / LN2 compact (16000,512)
  bf16* qkv = G; G += 25165824;             // (16,1024,1536)
  bf16* ql  = G; G += 2097152;              // (bh,256,64) scaled landmarks
  bf16* klT = G; G += 2097152;              // (bh,64,256)
  bf16* kT  = G; G += 8388608;              // (bh,64,1024)

  const long long sQKVb = 1572864;          // per-b stride in qkv (elements)
  const long long s16h = 16384,  s16b = 131072;   // (bh,256,64)-type
  const long long s64h = 65536,  s64b = 524288;   // (bh,256,256)/(bh,64,1024)

  embed_kernel<<<32000, 256, 0, stream>>>(xin, enc, pos, h);

  for (int i = 0; i < DEPTH_; i++){
    // LN1 -> padded bf16 xln (16,1024,512)
    ln_kernel<<<16384, 256, 0, stream>>>(h, xln, ln1s + i * 512, ln1b + i * 512, 1);

    // QKV: (16384,512)bf16 @ (512,1536)f32 -> qkv bf16
    run_gemm(stream, xln, qkvw + (long long)i * 786432, qkv, (const float*)nullptr,
             16384, 1536, 512, 512, 1536, 1536, 0,0, 0,0, 0,0, 1, 1, -1.f, 0.f, 0);

    landmark_kernel<<<8192, 256, 0, stream>>>(qkv, ql, klT);
    ktrans_kernel<<<32768, 256, 0, stream>>>(qkv, kT);

    // attn2 = softmax(ql @ klT) -> xat f32 (bh,256,256)
    run_gemm(stream, ql, klT, xat, (const float*)nullptr, 256, 256, 64, 64, 256, 256,
             s16b, s16h, s16b, s16h, s64b, s64h, 128, 8, -1.f, 0.f, 0);
    softmax_kernel<1, float><<<32768, 256, 0, stream>>>(xat);

    // attn3 (+@v) in 4 bh-chunks of 32 (4 b's each), probs in preg f32 (32,256,1024)
    for (int c = 0; c < 4; c++){
      run_gemm(stream, ql + c * 524288, kT + c * 2097152, preg, (const float*)nullptr,
               256, 1024, 64, 64, 1024, 1024,
               s16b, s16h, s64b, s64h, 2097152LL, 262144LL, 32, 8, -1.f, 0.f, 0);
      softmax_kernel<4, float><<<8192, 256, 0, stream>>>(preg);
      run_gemm(stream, preg, qkv + 1024 + (long long)c * 6291456, a3v + c * 524288,
               (const float*)nullptr, 256, 64, 1024, 1024, 1536, 64,
               2097152LL, 262144LL, sQKVb, 64LL, s16b, s16h, 32, 8, -1.f, 0.f, 0);
    }

    // pinv scale (global over all bh)
    zero_kernel<<<1, 64, 0, stream>>>(scal, 16);
    rcmax_kernel<<<128, 256, 0, stream>>>(xat, scal);

    // pinv + Wl = pinv @ a3v, in 4 bh-chunks of 32
    float* P[4] = { pz0, pz1, pz2, pz3 };
    for (int c = 0; c < 4; c++){
      const float* Xc = xat + (long long)c * 2097152;
      zinit_kernel<<<8192, 256, 0, stream>>>(Xc, P[0], scal);
      int zi = 0;
      for (int it = 0; it < 6; it++){
        int f0 = (zi + 1) & 3, f1 = (zi + 2) & 3, f2 = (zi + 3) & 3;
        run_gemm(stream, Xc, P[zi], P[f0], (const float*)nullptr, 256, 256, 256, 256, 256, 256,
                 s64b, s64h, s64b, s64h, s64b, s64h, 32, 8, -1.f, 0.f, 0);
        run_gemm(stream, P[f0], P[f0], P[f1], (const float*)nullptr, 256, 256, 256, 256, 256, 256,
                 s64b, s64h, s64b, s64h, s64b, s64h, 32, 8, 1.f, 7.f, 0);
        run_gemm(stream, P[f0], P[f1], P[f2], (const float*)nullptr, 256, 256, 256, 256, 256, 256,
                 s64b, s64h, s64b, s64h, s64b, s64h, 32, 8, 1.f, 15.f, 0);
        run_gemm(stream, P[zi], P[f2], P[f0], (const float*)nullptr, 256, 256, 256, 256, 256, 256,
                 s64b, s64h, s64b, s64h, s64b, s64h, 32, 8, 0.25f, 13.f, 0);
        zi = f0;
      }
      run_gemm(stream, P[zi], a3v + c * 524288, Wl + c * 524288, (const float*)nullptr,
               256, 64, 256, 256, 64, 64,
               s64b, s64h, s16b, s16h, s16b, s16h, 32, 8, -1.f, 0.f, 0);
    }

    // attn1 (+@Wl) in 4 n-chunks of 256 rows; probs alias xat (f32, bh,256,256)
    for (int nc = 0; nc < 4; nc++){
      const bf16* qrow = qkv + (long long)nc * 256 * 1536;
      run_gemm(stream, qrow, klT, xat, (const float*)nullptr, 256, 256, 64, 1536, 256, 256,
               sQKVb, 64LL, s16b, s16h, s64b, s64h, 128, 8, -SCALE_, 0.f, 0);
      softmax_kernel<1, float><<<32768, 256, 0, stream>>>(xat);
      run_gemm(stream, xat, Wl, preg + (long long)nc * 256 * 512, (const float*)nullptr,
               256, 64, 256, 256, 64, 512,
               s64b, s64h, s16b, s16h, s64b, 64LL, 128, 8, -1.f, 0.f, 0);
    }

    // + depthwise conv(v) into apre (=preg)
    conv_kernel<<<32768, 256, 0, stream>>>(qkv, ck + i * 264, preg);

    // h += apre[:, 24:, :] @ out_w + out_b
    run_gemm(stream, preg + PAD_ * 512, ow + (long long)i * 262144, h, ob + i * 512,
             1000, 512, 512, 512, 512, 512,
             524288LL, 0LL, 0LL, 0LL, 512000LL, 0LL, 16, 1, -1.f, 0.f, 1);

    // LN2 -> compact bf16 (16000,512)
    ln_kernel<<<16000, 256, 0, stream>>>(h, xln, ln2s + i * 512, ln2b + i * 512, 0);

    // FF in 4 column-chunks of 512: h += gelu(xln@w1c+b1c) @ w2c (+b2 once)
    for (int c = 0; c < 4; c++){
      run_gemm(stream, xln, w1 + (long long)i * 1048576 + c * 512, preg,
               b1 + i * 2048 + c * 512, 16000, 512, 512, 512, 2048, 512,
               0,0, 0,0, 0,0, 1, 1, -1.f, 0.f, 2);
      run_gemm(stream, preg, w2 + (long long)i * 1048576 + (long long)c * 512 * 512, h,
               (c == 0) ? (b2 + i * 512) : (const float*)nullptr,
               16000, 512, 512, 512, 512, 512, 0,0, 0,0, 0,0, 1, 1, -1.f, 0.f, 1);
    }
  }

  final_kernel<<<16, 256, 0, stream>>>(h, fw, fb, out);
}

// Round 4
// 18748.363 us; speedup vs baseline: 1.6539x; 1.6539x over previous
//
#include <hip/hip_runtime.h>
#include <hip/hip_bf16.h>
#include <math.h>

typedef unsigned short u16;
typedef unsigned int   u32;
typedef __attribute__((ext_vector_type(8))) short short8;
typedef __attribute__((ext_vector_type(4))) float f32x4;

#define L_ 1000
#define D_ 512
#define N_ 1024
#define DEPTH_ 6
#define PAD_ 24
#define SCALE_ 0.125f

__device__ inline float bf2f(u16 u){ union{u32 i; float f;} x; x.i = ((u32)u) << 16; return x.f; }
__device__ inline u16 f2bf(float f){
  union{float f; u32 i;} x; x.f = f;
  u32 r = x.i + 0x7fffu + ((x.i >> 16) & 1u);
  return (u16)(r >> 16);
}
__device__ inline float unpackSplit(u32 u){ return bf2f((u16)(u & 0xffffu)) + bf2f((u16)(u >> 16)); }
__device__ inline u32 packSplit(float v){
  u16 hi = f2bf(v);
  float r = v - bf2f(hi);
  u16 lo = f2bf(r);
  return (u32)hi | ((u32)lo << 16);
}

// ---------- block reductions (256 threads = 4 waves of 64) ----------
__device__ inline float blockSum256(float v, float* red){
  int t = threadIdx.x;
  #pragma unroll
  for (int o = 32; o > 0; o >>= 1) v += __shfl_down(v, o, 64);
  __syncthreads();
  if ((t & 63) == 0) red[t >> 6] = v;
  __syncthreads();
  return red[0] + red[1] + red[2] + red[3];
}
__device__ inline float blockMax256(float v, float* red){
  int t = threadIdx.x;
  #pragma unroll
  for (int o = 32; o > 0; o >>= 1) v = fmaxf(v, __shfl_down(v, o, 64));
  __syncthreads();
  if ((t & 63) == 0) red[t >> 6] = v;
  __syncthreads();
  return fmaxf(fmaxf(red[0], red[1]), fmaxf(red[2], red[3]));
}

// ---------- embedding ----------
__global__ __launch_bounds__(256) void embed_kernel(
    const int* __restrict__ x, const float* __restrict__ ee,
    const float* __restrict__ pe, float* __restrict__ h)
{
  long long i = (long long)blockIdx.x * 256 + threadIdx.x;  // 16*1000*512
  int d = (int)(i & 511);
  long long bl = i >> 9;
  int l = (int)(bl % 1000);
  int tok = x[bl];
  h[i] = ee[tok * D_ + d] + pe[l * D_ + d];
}

// ---------- layernorm: f32 in -> bf16(u16) out ----------
__global__ __launch_bounds__(256) void ln_kernel(
    const float* __restrict__ in, u16* __restrict__ out,
    const float* __restrict__ sc, const float* __restrict__ bi, int pad)
{
  __shared__ float red[4];
  int r = blockIdx.x, t = threadIdx.x;
  const float* row; u16* orow;
  if (pad){
    int bb = r >> 10, n = r & 1023;
    orow = out + (long long)r * D_;
    if (n < PAD_){ orow[t] = 0; orow[t + 256] = 0; return; }
    row = in + ((long long)bb * L_ + (n - PAD_)) * D_;
  } else {
    row  = in  + (long long)r * D_;
    orow = out + (long long)r * D_;
  }
  float x0 = row[t], x1 = row[t + 256];
  float mu = blockSum256(x0 + x1, red) * (1.f / 512.f);
  float d0 = x0 - mu, d1 = x1 - mu;
  float var = blockSum256(d0 * d0 + d1 * d1, red) * (1.f / 512.f);
  float rs = rsqrtf(var + 1e-5f);
  orow[t]       = f2bf(d0 * rs * sc[t]       + bi[t]);
  orow[t + 256] = f2bf(d1 * rs * sc[t + 256] + bi[t + 256]);
}

// ---------- weight transpose+convert: src f32 [K][N] -> dst bf16 [N][K] ----------
__global__ __launch_bounds__(256) void tconv_kernel(
    const float* __restrict__ src, u16* __restrict__ dst, int K, int N)
{
  __shared__ float tile[32][33];
  int kg = blockIdx.y << 5, ng = blockIdx.x << 5;
  int t = threadIdx.x;
  int kr = t >> 3, nc = (t & 7) << 2;
  float4 v = *(const float4*)(src + (long long)(kg + kr) * N + ng + nc);
  tile[kr][nc + 0] = v.x; tile[kr][nc + 1] = v.y;
  tile[kr][nc + 2] = v.z; tile[kr][nc + 3] = v.w;
  __syncthreads();
  int nr = t >> 3, kc = (t & 7) << 2;
  ushort4 o;
  o.x = f2bf(tile[kc + 0][nr]); o.y = f2bf(tile[kc + 1][nr]);
  o.z = f2bf(tile[kc + 2][nr]); o.w = f2bf(tile[kc + 3][nr]);
  *(ushort4*)(dst + (long long)(ng + nr) * K + kg + kc) = o;
}

// =========================================================================
// MFMA GEMM.  C = scale*(alpha*A[i,j] - A@B) (+bias, gelu, accumulate)
// MODE: 0 = plain bf16 A,B ; 1 = split A & split B ; 2 = split A, bf16 B
// BT:   0 = B source is [n][k] (ldb = n-row stride) ; 1 = B source is [k][n]
// OUT:  0 = f32 ; 1 = bf16 ; 2 = split-packed u32
// tile 128x128, BK=32, 256 threads (4 waves, 2x2 of 64x64 each)
// =========================================================================
template<int MODE, int BT, int OUT>
__global__ __launch_bounds__(256) void mgemm(
    const void* __restrict__ Av, const void* __restrict__ Bv, void* __restrict__ Cv,
    const float* __restrict__ bias,
    int M, int N, int K, int lda, int ldb, int ldc,
    long long sAb, long long sAh, long long sBb, long long sBh,
    long long sCb, long long sCh, int nh,
    float scale, float alpha, int flags)
{
  constexpr int APL = (MODE >= 1) ? 2 : 1;
  constexpr int BPL = (MODE == 1) ? 2 : 1;
  __shared__ u16 As[APL * 5120];   // [plane][row 128][k 40]
  __shared__ u16 Bs[BPL * 5120];   // [plane][n 128][k 40]

  const int t = threadIdx.x;
  const int bz = blockIdx.z;
  const int b = bz / nh, hh = bz - b * nh;
  const int m0 = blockIdx.y << 7, n0 = blockIdx.x << 7;

  const u16* A16 = nullptr; const u32* A32 = nullptr;
  if constexpr (MODE == 0) A16 = (const u16*)Av + (long long)b * sAb + (long long)hh * sAh;
  else                     A32 = (const u32*)Av + (long long)b * sAb + (long long)hh * sAh;
  const u16* B16 = nullptr; const u32* B32 = nullptr;
  if constexpr (MODE == 1) B32 = (const u32*)Bv + (long long)b * sBb + (long long)hh * sBh;
  else                     B16 = (const u16*)Bv + (long long)b * sBb + (long long)hh * sBh;

  f32x4 acc[4][4];
  #pragma unroll
  for (int i = 0; i < 4; i++)
    #pragma unroll
    for (int j = 0; j < 4; j++) acc[i][j] = (f32x4)0.f;

  const int w = t >> 6, lane = t & 63;
  const int wm = (w >> 1) << 6, wn = (w & 1) << 6;
  const int fr = lane & 15, ko = (lane >> 4) << 3;

  for (int k0 = 0; k0 < K; k0 += 32){
    // ---- stage A: [m][k] ----
    {
      int row = t >> 1, kq = (t & 1) << 4;
      int gr = m0 + row;
      if constexpr (MODE == 0){
        uint4 v0 = make_uint4(0,0,0,0), v1 = make_uint4(0,0,0,0);
        if (gr < M){
          const uint4* p = (const uint4*)(A16 + (long long)gr * lda + k0 + kq);
          v0 = p[0]; v1 = p[1];
        }
        *(uint4*)(As + row * 40 + kq)     = v0;
        *(uint4*)(As + row * 40 + kq + 8) = v1;
      } else {
        uint4 u0 = make_uint4(0,0,0,0), u1 = u0, u2 = u0, u3 = u0;
        if (gr < M){
          const uint4* p = (const uint4*)(A32 + (long long)gr * lda + k0 + kq);
          u0 = p[0]; u1 = p[1]; u2 = p[2]; u3 = p[3];
        }
        u32 e[16];
        *(uint4*)(e + 0) = u0; *(uint4*)(e + 4) = u1;
        *(uint4*)(e + 8) = u2; *(uint4*)(e + 12) = u3;
        u32 hw[8], lw[8];
        #pragma unroll
        for (int q = 0; q < 8; q++){
          u32 e0 = e[2*q], e1 = e[2*q+1];
          hw[q] = (e0 & 0xffffu) | (e1 << 16);
          lw[q] = (e0 >> 16)     | (e1 & 0xffff0000u);
        }
        uint4 h0; h0.x=hw[0]; h0.y=hw[1]; h0.z=hw[2]; h0.w=hw[3];
        uint4 h1; h1.x=hw[4]; h1.y=hw[5]; h1.z=hw[6]; h1.w=hw[7];
        uint4 l0; l0.x=lw[0]; l0.y=lw[1]; l0.z=lw[2]; l0.w=lw[3];
        uint4 l1; l1.x=lw[4]; l1.y=lw[5]; l1.z=lw[6]; l1.w=lw[7];
        *(uint4*)(As + row * 40 + kq)            = h0;
        *(uint4*)(As + row * 40 + kq + 8)        = h1;
        *(uint4*)(As + 5120 + row * 40 + kq)     = l0;
        *(uint4*)(As + 5120 + row * 40 + kq + 8) = l1;
      }
    }
    // ---- stage B: into [n][k] ----
    if constexpr (BT == 0){
      int nrow = t >> 1, kq = (t & 1) << 4;
      uint4 v0 = make_uint4(0,0,0,0), v1 = make_uint4(0,0,0,0);
      if (n0 + nrow < N){
        const uint4* p = (const uint4*)(B16 + (long long)(n0 + nrow) * ldb + k0 + kq);
        v0 = p[0]; v1 = p[1];
      }
      *(uint4*)(Bs + nrow * 40 + kq)     = v0;
      *(uint4*)(Bs + nrow * 40 + kq + 8) = v1;
    } else if constexpr (MODE != 1){
      int kr = t >> 3, nq = (t & 7) << 4;
      u16 e[16];
      #pragma unroll
      for (int j = 0; j < 16; j++) e[j] = 0;
      if (n0 + nq < N){
        const uint4* p = (const uint4*)(B16 + (long long)(k0 + kr) * ldb + n0 + nq);
        uint4 v0 = p[0], v1 = p[1];
        *(uint4*)(e + 0) = v0; *(uint4*)(e + 8) = v1;
      }
      #pragma unroll
      for (int j = 0; j < 16; j++) Bs[(nq + j) * 40 + kr] = e[j];
    } else {
      int kr = t >> 3, nq = (t & 7) << 4;
      u32 e[16];
      #pragma unroll
      for (int j = 0; j < 16; j++) e[j] = 0;
      if (n0 + nq < N){
        const uint4* p = (const uint4*)(B32 + (long long)(k0 + kr) * ldb + n0 + nq);
        uint4 u0 = p[0], u1 = p[1], u2 = p[2], u3 = p[3];
        *(uint4*)(e + 0) = u0; *(uint4*)(e + 4) = u1;
        *(uint4*)(e + 8) = u2; *(uint4*)(e + 12) = u3;
      }
      #pragma unroll
      for (int j = 0; j < 16; j++){
        Bs[(nq + j) * 40 + kr]        = (u16)(e[j] & 0xffffu);
        Bs[5120 + (nq + j) * 40 + kr] = (u16)(e[j] >> 16);
      }
    }
    __syncthreads();

    // ---- fragments + MFMA ----
    short8 ah[4], bh_[4];
    #pragma unroll
    for (int i = 0; i < 4; i++) ah[i] = *(const short8*)(As + (wm + i*16 + fr) * 40 + ko);
    #pragma unroll
    for (int j = 0; j < 4; j++) bh_[j] = *(const short8*)(Bs + (wn + j*16 + fr) * 40 + ko);
    if constexpr (MODE == 0){
      #pragma unroll
      for (int i = 0; i < 4; i++)
        #pragma unroll
        for (int j = 0; j < 4; j++)
          acc[i][j] = __builtin_amdgcn_mfma_f32_16x16x32_bf16(ah[i], bh_[j], acc[i][j], 0, 0, 0);
    } else if constexpr (MODE == 2){
      short8 al[4];
      #pragma unroll
      for (int i = 0; i < 4; i++) al[i] = *(const short8*)(As + 5120 + (wm + i*16 + fr) * 40 + ko);
      #pragma unroll
      for (int i = 0; i < 4; i++)
        #pragma unroll
        for (int j = 0; j < 4; j++){
          acc[i][j] = __builtin_amdgcn_mfma_f32_16x16x32_bf16(al[i], bh_[j], acc[i][j], 0, 0, 0);
          acc[i][j] = __builtin_amdgcn_mfma_f32_16x16x32_bf16(ah[i], bh_[j], acc[i][j], 0, 0, 0);
        }
    } else {
      short8 al[4], bl[4];
      #pragma unroll
      for (int i = 0; i < 4; i++) al[i] = *(const short8*)(As + 5120 + (wm + i*16 + fr) * 40 + ko);
      #pragma unroll
      for (int j = 0; j < 4; j++) bl[j] = *(const short8*)(Bs + 5120 + (wn + j*16 + fr) * 40 + ko);
      #pragma unroll
      for (int i = 0; i < 4; i++)
        #pragma unroll
        for (int j = 0; j < 4; j++){
          acc[i][j] = __builtin_amdgcn_mfma_f32_16x16x32_bf16(al[i], bh_[j], acc[i][j], 0, 0, 0);
          acc[i][j] = __builtin_amdgcn_mfma_f32_16x16x32_bf16(ah[i], bl[j], acc[i][j], 0, 0, 0);
          acc[i][j] = __builtin_amdgcn_mfma_f32_16x16x32_bf16(ah[i], bh_[j], acc[i][j], 0, 0, 0);
        }
    }
    __syncthreads();
  }

  // ---- epilogue ----
  const long long coff = (long long)b * sCb + (long long)hh * sCh;
  #pragma unroll
  for (int i = 0; i < 4; i++){
    #pragma unroll
    for (int j = 0; j < 4; j++){
      #pragma unroll
      for (int r = 0; r < 4; r++){
        int row = m0 + wm + i*16 + ((lane >> 4) << 2) + r;
        int col = n0 + wn + j*16 + fr;
        if (row < M && col < N){
          float v = acc[i][j][r];
          float at = 0.f;
          if (alpha != 0.f){
            if constexpr (MODE == 0) at = bf2f(A16[(long long)row * lda + col]);
            else                     at = unpackSplit(A32[(long long)row * lda + col]);
          }
          v = scale * (alpha * at - v);
          if (bias) v += bias[col];
          if (flags & 2) v = 0.5f * v * (1.f + erff(v * 0.7071067811865476f));
          if constexpr (OUT == 0){
            float* cp = (float*)Cv + coff + (long long)row * ldc + col;
            if (flags & 1) v += *cp;
            *cp = v;
          } else if constexpr (OUT == 1){
            u16* cp = (u16*)Cv + coff + (long long)row * ldc + col;
            if (flags & 1) v += bf2f(*cp);
            *cp = f2bf(v);
          } else {
            u32* cp = (u32*)Cv + coff + (long long)row * ldc + col;
            *cp = packSplit(v);
          }
        }
      }
    }
  }
}

// ---------- bf16 row softmax, row length = PER*256, in place ----------
template<int PER>
__global__ __launch_bounds__(256) void softmax_bf16(u16* __restrict__ d)
{
  __shared__ float red[4];
  long long r = blockIdx.x;
  u16* row = d + r * (PER * 256);
  int t = threadIdx.x;
  float vals[PER];
  float mx = -3.4e38f;
  #pragma unroll
  for (int i = 0; i < PER; i++){ vals[i] = bf2f(row[t + i * 256]); mx = fmaxf(mx, vals[i]); }
  mx = blockMax256(mx, red);
  float s = 0.f;
  #pragma unroll
  for (int i = 0; i < PER; i++){ vals[i] = expf(vals[i] - mx); s += vals[i]; }
  s = blockSum256(s, red);
  float inv = 1.f / s;
  #pragma unroll
  for (int i = 0; i < PER; i++) row[t + i * 256] = f2bf(vals[i] * inv);
}

// ---------- f32 softmax over 256, write split-packed (in place, attn2) ----------
__global__ __launch_bounds__(256) void softmax_split(float* __restrict__ d)
{
  __shared__ float red[4];
  long long r = blockIdx.x;
  float* row = d + r * 256;
  int t = threadIdx.x;
  float val = row[t];
  float mx = blockMax256(val, red);
  val = expf(val - mx);
  float s = blockSum256(val, red);
  float o = val / s;
  __syncthreads();
  ((u32*)row)[t] = packSplit(o);
}

// ---------- landmarks: ql (scaled) and kl, both (bh,256,64) bf16 ----------
__global__ __launch_bounds__(256) void landmark_kernel(
    const u16* __restrict__ qkv, u16* __restrict__ ql, u16* __restrict__ kl)
{
  long long i = (long long)blockIdx.x * 256 + threadIdx.x;  // 128*256*64
  int d = (int)(i & 63);
  long long r = i >> 6;
  int m = (int)(r & 255);
  int bh = (int)(r >> 8);
  int hh = bh & 7, b = bh >> 3;
  const u16* base = qkv + ((long long)b * N_ + m * 4) * 1536 + hh * 64 + d;
  float qs = bf2f(base[0]) + bf2f(base[1536]) + bf2f(base[3072]) + bf2f(base[4608]);
  float ks = bf2f(base[512]) + bf2f(base[2048]) + bf2f(base[3584]) + bf2f(base[5120]);
  ql[i] = f2bf(qs * 0.25f * SCALE_);
  kl[i] = f2bf(ks * 0.25f);
}

// ---------- pinv scale helpers ----------
__global__ void zero_kernel(float* p, int n){
  int i = blockIdx.x * 64 + threadIdx.x;
  if (i < n) p[i] = 0.f;
}
__global__ __launch_bounds__(256) void rcmax_kernel(
    const u32* __restrict__ x, float* __restrict__ scal)
{
  __shared__ float red[4];
  int bh = blockIdx.x, t = threadIdx.x;
  const u32* X = x + (long long)bh * 65536;
  float cs = 0.f, rs = 0.f;
  for (int m = 0; m < 256; m++) cs += fabsf(unpackSplit(X[m * 256 + t]));
  for (int j = 0; j < 256; j++) rs += fabsf(unpackSplit(X[t * 256 + j]));
  float cmax = blockMax256(cs, red);
  float rmax = blockMax256(rs, red);
  if (t == 0){
    atomicMax((unsigned int*)(scal + 0), __float_as_uint(rmax));
    atomicMax((unsigned int*)(scal + 1), __float_as_uint(cmax));
  }
}
// z = x^T * inv over a 64-bh chunk (grid 16384)
__global__ __launch_bounds__(256) void zinit_kernel(
    const u32* __restrict__ x, u32* __restrict__ z, const float* __restrict__ scal)
{
  float inv = 1.f / (scal[0] * scal[1]);
  long long i = (long long)blockIdx.x * 256 + threadIdx.x;  // 64*65536
  long long bh = i >> 16;
  int ij = (int)(i & 65535);
  int ii = ij >> 8, jj = ij & 255;
  z[(bh << 16) + (ii << 8) + jj] = packSplit(unpackSplit(x[(bh << 16) + (jj << 8) + ii]) * inv);
}

// ---------- depthwise conv (k=33), writes apre (bf16) ----------
__global__ __launch_bounds__(256) void conv_kernel(
    const u16* __restrict__ qkv, const float* __restrict__ ck, u16* __restrict__ out)
{
  long long i = (long long)blockIdx.x * 256 + threadIdx.x;  // 16*1024*512
  int c = (int)(i & 511);
  long long r = i >> 9;
  int n = (int)(r & 1023);
  int b = (int)(r >> 10);
  int hh = c >> 6;
  const float* kk = ck + hh * 33;
  float acc = 0.f;
  #pragma unroll
  for (int t = 0; t < 33; t++){
    int nn = n + t - 16;
    if (nn >= 0 && nn < N_)
      acc += bf2f(qkv[((long long)b * N_ + nn) * 1536 + 1024 + c]) * kk[t];
  }
  out[i] = f2bf(acc);
}

// ---------- final ----------
__global__ __launch_bounds__(256) void final_kernel(
    const float* __restrict__ h, const float* __restrict__ w,
    const float* __restrict__ bb, float* __restrict__ out)
{
  __shared__ float red[4];
  int b = blockIdx.x, t = threadIdx.x;
  const float* hp = h + (long long)b * (L_ * D_);
  float acc = 0.f;
  for (int i = t; i < L_ * D_; i += 256) acc += hp[i] * w[i];
  acc = blockSum256(acc, red);
  if (t == 0) out[b] = acc + bb[0];
}

// ---------- host wrapper ----------
template<int MODE, int BT, int OUT>
static inline void mg(hipStream_t st, const void* A, const void* B, void* C,
  const float* bias, int M, int N, int K, int lda, int ldb, int ldc,
  long long sAb, long long sAh, long long sBb, long long sBh,
  long long sCb, long long sCh, int batch, int nh,
  float scale, float alpha, int flags)
{
  dim3 g((N + 127) >> 7, (M + 127) >> 7, batch);
  mgemm<MODE, BT, OUT><<<g, 256, 0, st>>>(A, B, C, bias, M, N, K, lda, ldb, ldc,
      sAb, sAh, sBb, sBh, sCb, sCh, nh, scale, alpha, flags);
}

extern "C" void kernel_launch(void* const* d_in, const int* in_sizes, int n_in,
                              void* d_out, int out_size, void* d_ws, size_t ws_size,
                              hipStream_t stream)
{
  const int*   xin  = (const int*)d_in[0];
  const float* enc  = (const float*)d_in[1];
  const float* pos  = (const float*)d_in[2];
  const float* ln1s = (const float*)d_in[3];
  const float* ln1b = (const float*)d_in[4];
  const float* qkvw = (const float*)d_in[5];
  const float* ow   = (const float*)d_in[6];
  const float* ob   = (const float*)d_in[7];
  const float* ck   = (const float*)d_in[8];
  const float* ln2s = (const float*)d_in[9];
  const float* ln2b = (const float*)d_in[10];
  const float* w1   = (const float*)d_in[11];
  const float* b1   = (const float*)d_in[12];
  const float* w2   = (const float*)d_in[13];
  const float* b2   = (const float*)d_in[14];
  const float* fw   = (const float*)d_in[15];
  const float* fb   = (const float*)d_in[16];
  float* out = (float*)d_out;

  // ---- workspace layout: 206,831,680 bytes ----
  const size_t NEED = 206831680ULL;
  if (ws_size < NEED) return;

  char* P = (char*)d_ws;
  float* h    = (float*)P; P += 32768000;      // (16,1000,512) f32
  u32*   X    = (u32*)P;   P += 33554432;      // attn2 split-packed (128,256,256)
  u16*   probs= (u16*)P;   P += 33554432;      // bf16: attn3/attn1 probs chunk, FF1 act
  u16*   xln  = (u16*)P;   P += 16777216;      // bf16 LN out
  u16*   apre = (u16*)P;   P += 16777216;      // bf16 (16,1024,512)
  u16*   qkv  = (u16*)P;   P += 50331648;      // bf16 (16,1024,1536)
  u16*   ql   = (u16*)P;   P += 4194304;       // (bh,256,64)
  u16*   kl   = (u16*)P;   P += 4194304;       // (bh,256,64)
  u16*   a3v  = (u16*)P;   P += 4194304;       // (bh,256,64)
  u16*   Wl   = (u16*)P;   P += 4194304;       // (bh,256,64)
  u16*   qkvwT= (u16*)P;   P += 1572864;       // (1536,512)
  u16*   owT  = (u16*)P;   P += 524288;        // (512,512)
  u16*   w1T  = (u16*)P;   P += 2097152;       // (2048,512)
  u16*   w2T  = (u16*)P;   P += 2097152;       // (512,2048)
  float* scal = (float*)P; P += 64;
  // pinv rotation buffers alias probs+xln+apre (dead during pinv)
  u32* pz[4];
  for (int j = 0; j < 4; j++) pz[j] = (u32*)probs + (long long)j * 4194304;

  embed_kernel<<<32000, 256, 0, stream>>>(xin, enc, pos, h);

  for (int i = 0; i < DEPTH_; i++){
    // weight transposes (f32 -> bf16 [N][K])
    tconv_kernel<<<dim3(48, 16), 256, 0, stream>>>(qkvw + (long long)i * 786432, qkvwT, 512, 1536);
    tconv_kernel<<<dim3(16, 16), 256, 0, stream>>>(ow + (long long)i * 262144, owT, 512, 512);
    tconv_kernel<<<dim3(64, 16), 256, 0, stream>>>(w1 + (long long)i * 1048576, w1T, 512, 2048);
    tconv_kernel<<<dim3(16, 64), 256, 0, stream>>>(w2 + (long long)i * 1048576, w2T, 2048, 512);

    // LN1 -> padded bf16 xln (16,1024,512)
    ln_kernel<<<16384, 256, 0, stream>>>(h, xln, ln1s + i * 512, ln1b + i * 512, 1);

    // QKV: (16384,512) @ (512,1536) -> qkv bf16
    mg<0,0,1>(stream, xln, qkvwT, qkv, nullptr, 16384, 1536, 512, 512, 512, 1536,
              0,0, 0,0, 0,0, 1, 1, -1.f, 0.f, 0);

    landmark_kernel<<<8192, 256, 0, stream>>>(qkv, ql, kl);

    // attn2 logits -> X (f32), then softmax -> split-packed
    mg<0,0,0>(stream, ql, kl, (float*)X, nullptr, 256, 256, 64, 64, 64, 256,
              131072, 16384, 131072, 16384, 524288, 65536, 128, 8, -1.f, 0.f, 0);
    softmax_split<<<32768, 256, 0, stream>>>((float*)X);

    // attn3 (+@v) in 2 bh-chunks of 64
    for (int c = 0; c < 2; c++){
      mg<0,0,1>(stream, ql + (long long)c * 64 * 16384, qkv + (long long)c * 8 * 1572864 + 512,
                probs, nullptr, 256, 1024, 64, 64, 1536, 1024,
                131072, 16384, 1572864, 64, 2097152, 262144, 64, 8, -1.f, 0.f, 0);
      softmax_bf16<4><<<16384, 256, 0, stream>>>(probs);
      mg<0,1,1>(stream, probs, qkv + (long long)c * 8 * 1572864 + 1024,
                a3v + (long long)c * 64 * 16384, nullptr, 256, 64, 1024, 1024, 1536, 64,
                2097152, 262144, 1572864, 64, 131072, 16384, 64, 8, -1.f, 0.f, 0);
    }

    // pinv scaling factors (global over all bh)
    zero_kernel<<<1, 64, 0, stream>>>(scal, 16);
    rcmax_kernel<<<128, 256, 0, stream>>>(X, scal);

    // pinv (split precision) + Wl, in 2 bh-chunks of 64
    for (int c = 0; c < 2; c++){
      const u32* Xc = X + (long long)c * 64 * 65536;
      zinit_kernel<<<16384, 256, 0, stream>>>(Xc, pz[0], scal);
      int zi = 0;
      for (int it = 0; it < 6; it++){
        int f0 = (zi + 1) & 3, f1 = (zi + 2) & 3, f2 = (zi + 3) & 3;
        mg<1,1,2>(stream, Xc, pz[zi], pz[f0], nullptr, 256, 256, 256, 256, 256, 256,
                  65536, 0, 65536, 0, 65536, 0, 64, 1, -1.f, 0.f, 0);
        mg<1,1,2>(stream, pz[f0], pz[f0], pz[f1], nullptr, 256, 256, 256, 256, 256, 256,
                  65536, 0, 65536, 0, 65536, 0, 64, 1, 1.f, 7.f, 0);
        mg<1,1,2>(stream, pz[f0], pz[f1], pz[f2], nullptr, 256, 256, 256, 256, 256, 256,
                  65536, 0, 65536, 0, 65536, 0, 64, 1, 1.f, 15.f, 0);
        mg<1,1,2>(stream, pz[zi], pz[f2], pz[f0], nullptr, 256, 256, 256, 256, 256, 256,
                  65536, 0, 65536, 0, 65536, 0, 64, 1, 0.25f, 13.f, 0);
        zi = f0;
      }
      mg<2,1,1>(stream, pz[zi], a3v + (long long)c * 64 * 16384, Wl + (long long)c * 64 * 16384,
                nullptr, 256, 64, 256, 256, 64, 64,
                65536, 0, 16384, 0, 16384, 0, 64, 1, -1.f, 0.f, 0);
    }

    // depthwise conv(v) -> apre (bf16, overwrite)
    conv_kernel<<<32768, 256, 0, stream>>>(qkv, ck + i * 264, apre);

    // attn1 (+@Wl accumulate into apre) in 2 b-chunks of 8
    for (int c = 0; c < 2; c++){
      mg<0,0,1>(stream, qkv + (long long)c * 8 * 1572864, kl + (long long)c * 8 * 131072,
                probs, nullptr, 1024, 256, 64, 1536, 64, 256,
                1572864, 64, 131072, 16384, 2097152, 262144, 64, 8, -SCALE_, 0.f, 0);
      softmax_bf16<1><<<65536, 256, 0, stream>>>(probs);
      mg<0,1,1>(stream, probs, Wl + (long long)c * 64 * 16384,
                apre + (long long)c * 8 * 524288, nullptr, 1024, 64, 256, 256, 64, 512,
                2097152, 262144, 131072, 16384, 524288, 64, 64, 8, -1.f, 0.f, 1);
    }

    // h += apre[:, 24:, :] @ out_w + out_b
    mg<0,0,0>(stream, apre + PAD_ * 512, owT, h, ob + i * 512,
              1000, 512, 512, 512, 512, 512,
              524288, 0, 0, 0, 512000, 0, 16, 1, -1.f, 0.f, 1);

    // LN2 -> compact bf16 (16000,512)
    ln_kernel<<<16000, 256, 0, stream>>>(h, xln, ln2s + i * 512, ln2b + i * 512, 0);

    // FF in 2 N-chunks of 1024
    for (int c = 0; c < 2; c++){
      mg<0,0,1>(stream, xln, w1T + (long long)c * 1024 * 512, probs,
                b1 + i * 2048 + c * 1024, 16000, 1024, 512, 512, 512, 1024,
                0,0, 0,0, 0,0, 1, 1, -1.f, 0.f, 2);
      mg<0,0,0>(stream, probs, w2T + (long long)c * 1024, h,
                (c == 0) ? (b2 + i * 512) : nullptr,
                16000, 512, 1024, 1024, 2048, 512,
                0,0, 0,0, 0,0, 1, 1, -1.f, 0.f, 1);
    }
  }

  final_kernel<<<16, 256, 0, stream>>>(h, fw, fb, out);
}

// Round 5
// 12819.206 us; speedup vs baseline: 2.4189x; 1.4625x over previous
//
#include <hip/hip_runtime.h>
#include <hip/hip_bf16.h>
#include <math.h>

typedef unsigned short u16;
typedef unsigned int   u32;
typedef __attribute__((ext_vector_type(8))) short short8;
typedef __attribute__((ext_vector_type(4))) float f32x4;

#define L_ 1000
#define D_ 512
#define N_ 1024
#define DEPTH_ 6
#define PAD_ 24
#define SCALE_ 0.125f

__device__ inline float bf2f(u16 u){ union{u32 i; float f;} x; x.i = ((u32)u) << 16; return x.f; }
__device__ inline u16 f2bf(float f){
  union{float f; u32 i;} x; x.f = f;
  u32 r = x.i + 0x7fffu + ((x.i >> 16) & 1u);
  return (u16)(r >> 16);
}

// ---------- block reductions (256 threads = 4 waves of 64) ----------
__device__ inline float blockSum256(float v, float* red){
  int t = threadIdx.x;
  #pragma unroll
  for (int o = 32; o > 0; o >>= 1) v += __shfl_down(v, o, 64);
  __syncthreads();
  if ((t & 63) == 0) red[t >> 6] = v;
  __syncthreads();
  return red[0] + red[1] + red[2] + red[3];
}
__device__ inline float blockMax256(float v, float* red){
  int t = threadIdx.x;
  #pragma unroll
  for (int o = 32; o > 0; o >>= 1) v = fmaxf(v, __shfl_down(v, o, 64));
  __syncthreads();
  if ((t & 63) == 0) red[t >> 6] = v;
  __syncthreads();
  return fmaxf(fmaxf(red[0], red[1]), fmaxf(red[2], red[3]));
}

// ---------- embedding ----------
__global__ __launch_bounds__(256) void embed_kernel(
    const int* __restrict__ x, const float* __restrict__ ee,
    const float* __restrict__ pe, float* __restrict__ h)
{
  long long i = (long long)blockIdx.x * 256 + threadIdx.x;  // 16*1000*512
  int d = (int)(i & 511);
  long long bl = i >> 9;
  int l = (int)(bl % 1000);
  int tok = x[bl];
  h[i] = ee[tok * D_ + d] + pe[l * D_ + d];
}

// ---------- layernorm: f32 in -> bf16(u16) out ----------
__global__ __launch_bounds__(256) void ln_kernel(
    const float* __restrict__ in, u16* __restrict__ out,
    const float* __restrict__ sc, const float* __restrict__ bi, int pad)
{
  __shared__ float red[4];
  int r = blockIdx.x, t = threadIdx.x;
  const float* row; u16* orow;
  if (pad){
    int bb = r >> 10, n = r & 1023;
    orow = out + (long long)r * D_;
    if (n < PAD_){ orow[t] = 0; orow[t + 256] = 0; return; }
    row = in + ((long long)bb * L_ + (n - PAD_)) * D_;
  } else {
    row  = in  + (long long)r * D_;
    orow = out + (long long)r * D_;
  }
  float x0 = row[t], x1 = row[t + 256];
  float mu = blockSum256(x0 + x1, red) * (1.f / 512.f);
  float d0 = x0 - mu, d1 = x1 - mu;
  float var = blockSum256(d0 * d0 + d1 * d1, red) * (1.f / 512.f);
  float rs = rsqrtf(var + 1e-5f);
  orow[t]       = f2bf(d0 * rs * sc[t]       + bi[t]);
  orow[t + 256] = f2bf(d1 * rs * sc[t + 256] + bi[t + 256]);
}

// ---------- weight transpose+convert: src f32 [K][N] -> dst bf16 [N][K] ----------
__global__ __launch_bounds__(256) void tconv_kernel(
    const float* __restrict__ src, u16* __restrict__ dst, int K, int N)
{
  __shared__ float tile[32][33];
  int kg = blockIdx.y << 5, ng = blockIdx.x << 5;
  int t = threadIdx.x;
  int kr = t >> 3, nc = (t & 7) << 2;
  float4 v = *(const float4*)(src + (long long)(kg + kr) * N + ng + nc);
  tile[kr][nc + 0] = v.x; tile[kr][nc + 1] = v.y;
  tile[kr][nc + 2] = v.z; tile[kr][nc + 3] = v.w;
  __syncthreads();
  int nr = t >> 3, kc = (t & 7) << 2;
  ushort4 o;
  o.x = f2bf(tile[kc + 0][nr]); o.y = f2bf(tile[kc + 1][nr]);
  o.z = f2bf(tile[kc + 2][nr]); o.w = f2bf(tile[kc + 3][nr]);
  *(ushort4*)(dst + (long long)(ng + nr) * K + kg + kc) = o;
}

// =========================================================================
// MFMA GEMM (bf16 x bf16, f32 acc).
// C = scale*(alpha*A[i,j] + beta*B[i,j] - A@B)  (+bias, gelu, acc, -I)
// BT: 0 = B source [n][k] (ldb = n-row stride) ; 1 = B source [k][n]
// OUT: 0 = f32 ; 1 = bf16
// flags: 1 = accumulate into C, 2 = exact gelu, 4 = subtract identity
// tile 128x128, BK=32, 256 threads (4 waves, 2x2 of 64x64)
// =========================================================================
template<int BT, int OUT>
__global__ __launch_bounds__(256) void mgemm(
    const u16* __restrict__ A16, const u16* __restrict__ B16, void* __restrict__ Cv,
    const float* __restrict__ bias,
    int M, int N, int K, int lda, int ldb, int ldc,
    long long sAb, long long sAh, long long sBb, long long sBh,
    long long sCb, long long sCh, int nh,
    float scale, float alpha, float beta, int flags)
{
  __shared__ u16 As[5120];   // [row 128][k 40]
  __shared__ u16 Bs[5120];   // [n 128][k 40]

  const int t = threadIdx.x;
  const int bz = blockIdx.z;
  const int b = bz / nh, hh = bz - b * nh;
  const int m0 = blockIdx.y << 7, n0 = blockIdx.x << 7;

  const u16* A = A16 + (long long)b * sAb + (long long)hh * sAh;
  const u16* B = B16 + (long long)b * sBb + (long long)hh * sBh;

  f32x4 acc[4][4];
  #pragma unroll
  for (int i = 0; i < 4; i++)
    #pragma unroll
    for (int j = 0; j < 4; j++) acc[i][j] = (f32x4)0.f;

  const int w = t >> 6, lane = t & 63;
  const int wm = (w >> 1) << 6, wn = (w & 1) << 6;
  const int fr = lane & 15, ko = (lane >> 4) << 3;

  for (int k0 = 0; k0 < K; k0 += 32){
    // ---- stage A: [m][k] ----
    {
      int row = t >> 1, kq = (t & 1) << 4;
      int gr = m0 + row;
      uint4 v0 = make_uint4(0,0,0,0), v1 = make_uint4(0,0,0,0);
      if (gr < M){
        const uint4* p = (const uint4*)(A + (long long)gr * lda + k0 + kq);
        v0 = p[0]; v1 = p[1];
      }
      *(uint4*)(As + row * 40 + kq)     = v0;
      *(uint4*)(As + row * 40 + kq + 8) = v1;
    }
    // ---- stage B into [n][k] ----
    if constexpr (BT == 0){
      int nrow = t >> 1, kq = (t & 1) << 4;
      uint4 v0 = make_uint4(0,0,0,0), v1 = make_uint4(0,0,0,0);
      if (n0 + nrow < N){
        const uint4* p = (const uint4*)(B + (long long)(n0 + nrow) * ldb + k0 + kq);
        v0 = p[0]; v1 = p[1];
      }
      *(uint4*)(Bs + nrow * 40 + kq)     = v0;
      *(uint4*)(Bs + nrow * 40 + kq + 8) = v1;
    } else {
      int kr = t >> 3, nq = (t & 7) << 4;
      u16 e[16];
      #pragma unroll
      for (int j = 0; j < 16; j++) e[j] = 0;
      if (n0 + nq < N){
        const uint4* p = (const uint4*)(B + (long long)(k0 + kr) * ldb + n0 + nq);
        uint4 v0 = p[0], v1 = p[1];
        *(uint4*)(e + 0) = v0; *(uint4*)(e + 8) = v1;
      }
      #pragma unroll
      for (int j = 0; j < 16; j++) Bs[(nq + j) * 40 + kr] = e[j];
    }
    __syncthreads();

    // ---- fragments + MFMA ----
    short8 ah[4], bh_[4];
    #pragma unroll
    for (int i = 0; i < 4; i++) ah[i] = *(const short8*)(As + (wm + i*16 + fr) * 40 + ko);
    #pragma unroll
    for (int j = 0; j < 4; j++) bh_[j] = *(const short8*)(Bs + (wn + j*16 + fr) * 40 + ko);
    #pragma unroll
    for (int i = 0; i < 4; i++)
      #pragma unroll
      for (int j = 0; j < 4; j++)
        acc[i][j] = __builtin_amdgcn_mfma_f32_16x16x32_bf16(ah[i], bh_[j], acc[i][j], 0, 0, 0);
    __syncthreads();
  }

  // ---- epilogue ----
  const long long coff = (long long)b * sCb + (long long)hh * sCh;
  #pragma unroll
  for (int i = 0; i < 4; i++){
    #pragma unroll
    for (int j = 0; j < 4; j++){
      #pragma unroll
      for (int r = 0; r < 4; r++){
        int row = m0 + wm + i*16 + ((lane >> 4) << 2) + r;
        int col = n0 + wn + j*16 + fr;
        if (row < M && col < N){
          float v = acc[i][j][r];
          float at = (alpha != 0.f) ? bf2f(A[(long long)row * lda + col]) : 0.f;
          float bt = (beta  != 0.f) ? bf2f(B[(long long)row * ldb + col]) : 0.f;
          v = scale * (alpha * at + beta * bt - v);
          if (flags & 4) v -= (row == col) ? 1.f : 0.f;
          if (bias) v += bias[col];
          if (flags & 2) v = 0.5f * v * (1.f + erff(v * 0.7071067811865476f));
          if constexpr (OUT == 0){
            float* cp = (float*)Cv + coff + (long long)row * ldc + col;
            if (flags & 1) v += *cp;
            *cp = v;
          } else {
            u16* cp = (u16*)Cv + coff + (long long)row * ldc + col;
            if (flags & 1) v += bf2f(*cp);
            *cp = f2bf(v);
          }
        }
      }
    }
  }
}

// ---------- bf16 row softmax, row length = PER*256, in place ----------
template<int PER>
__global__ __launch_bounds__(256) void softmax_bf16(u16* __restrict__ d)
{
  __shared__ float red[4];
  long long r = blockIdx.x;
  u16* row = d + r * (PER * 256);
  int t = threadIdx.x;
  float vals[PER];
  float mx = -3.4e38f;
  #pragma unroll
  for (int i = 0; i < PER; i++){ vals[i] = bf2f(row[t + i * 256]); mx = fmaxf(mx, vals[i]); }
  mx = blockMax256(mx, red);
  float s = 0.f;
  #pragma unroll
  for (int i = 0; i < PER; i++){ vals[i] = expf(vals[i] - mx); s += vals[i]; }
  s = blockSum256(s, red);
  float inv = 1.f / s;
  #pragma unroll
  for (int i = 0; i < PER; i++) row[t + i * 256] = f2bf(vals[i] * inv);
}

// ---------- f32 softmax over 256 -> bf16 out (attn2) ----------
__global__ __launch_bounds__(256) void softmax_f2b(
    const float* __restrict__ in, u16* __restrict__ out)
{
  __shared__ float red[4];
  long long r = blockIdx.x;
  const float* row = in + r * 256;
  int t = threadIdx.x;
  float val = row[t];
  float mx = blockMax256(val, red);
  val = expf(val - mx);
  float s = blockSum256(val, red);
  out[r * 256 + t] = f2bf(val / s);
}

// ---------- landmarks: ql (scaled) and kl, both (bh,256,64) bf16 ----------
__global__ __launch_bounds__(256) void landmark_kernel(
    const u16* __restrict__ qkv, u16* __restrict__ ql, u16* __restrict__ kl)
{
  long long i = (long long)blockIdx.x * 256 + threadIdx.x;  // 128*256*64
  int d = (int)(i & 63);
  long long r = i >> 6;
  int m = (int)(r & 255);
  int bh = (int)(r >> 8);
  int hh = bh & 7, b = bh >> 3;
  const u16* base = qkv + ((long long)b * N_ + m * 4) * 1536 + hh * 64 + d;
  float qs = bf2f(base[0]) + bf2f(base[1536]) + bf2f(base[3072]) + bf2f(base[4608]);
  float ks = bf2f(base[512]) + bf2f(base[2048]) + bf2f(base[3584]) + bf2f(base[5120]);
  ql[i] = f2bf(qs * 0.25f * SCALE_);
  kl[i] = f2bf(ks * 0.25f);
}

// ---------- pinv scale helpers ----------
__global__ void zero_kernel(float* p, int n){
  int i = blockIdx.x * 64 + threadIdx.x;
  if (i < n) p[i] = 0.f;
}
__global__ __launch_bounds__(256) void rcmax_kernel(
    const u16* __restrict__ x, float* __restrict__ scal)
{
  __shared__ float red[4];
  int bh = blockIdx.x, t = threadIdx.x;
  const u16* X = x + (long long)bh * 65536;
  float cs = 0.f, rs = 0.f;
  for (int m = 0; m < 256; m++) cs += fabsf(bf2f(X[m * 256 + t]));
  for (int j = 0; j < 256; j++) rs += fabsf(bf2f(X[t * 256 + j]));
  float cmax = blockMax256(cs, red);
  float rmax = blockMax256(rs, red);
  if (t == 0){
    atomicMax((unsigned int*)(scal + 0), __float_as_uint(rmax));
    atomicMax((unsigned int*)(scal + 1), __float_as_uint(cmax));
  }
}
// z = x^T * inv over all 128 bh (grid 32768)
__global__ __launch_bounds__(256) void zinit_kernel(
    const u16* __restrict__ x, u16* __restrict__ z, const float* __restrict__ scal)
{
  float inv = 1.f / (scal[0] * scal[1]);
  long long i = (long long)blockIdx.x * 256 + threadIdx.x;  // 128*65536
  long long bh = i >> 16;
  int ij = (int)(i & 65535);
  int ii = ij >> 8, jj = ij & 255;
  z[(bh << 16) + (ii << 8) + jj] = f2bf(bf2f(x[(bh << 16) + (jj << 8) + ii]) * inv);
}

// ---------- depthwise conv (k=33), writes apre (bf16) ----------
__global__ __launch_bounds__(256) void conv_kernel(
    const u16* __restrict__ qkv, const float* __restrict__ ck, u16* __restrict__ out)
{
  long long i = (long long)blockIdx.x * 256 + threadIdx.x;  // 16*1024*512
  int c = (int)(i & 511);
  long long r = i >> 9;
  int n = (int)(r & 1023);
  int b = (int)(r >> 10);
  int hh = c >> 6;
  const float* kk = ck + hh * 33;
  float acc = 0.f;
  #pragma unroll
  for (int t = 0; t < 33; t++){
    int nn = n + t - 16;
    if (nn >= 0 && nn < N_)
      acc += bf2f(qkv[((long long)b * N_ + nn) * 1536 + 1024 + c]) * kk[t];
  }
  out[i] = f2bf(acc);
}

// ---------- final ----------
__global__ __launch_bounds__(256) void final_kernel(
    const float* __restrict__ h, const float* __restrict__ w,
    const float* __restrict__ bb, float* __restrict__ out)
{
  __shared__ float red[4];
  int b = blockIdx.x, t = threadIdx.x;
  const float* hp = h + (long long)b * (L_ * D_);
  float acc = 0.f;
  for (int i = t; i < L_ * D_; i += 256) acc += hp[i] * w[i];
  acc = blockSum256(acc, red);
  if (t == 0) out[b] = acc + bb[0];
}

// ---------- host wrapper ----------
template<int BT, int OUT>
static inline void mg(hipStream_t st, const void* A, const void* B, void* C,
  const float* bias, int M, int N, int K, int lda, int ldb, int ldc,
  long long sAb, long long sAh, long long sBb, long long sBh,
  long long sCb, long long sCh, int batch, int nh,
  float scale, float alpha, float beta, int flags)
{
  dim3 g((N + 127) >> 7, (M + 127) >> 7, batch);
  mgemm<BT, OUT><<<g, 256, 0, st>>>((const u16*)A, (const u16*)B, C, bias,
      M, N, K, lda, ldb, ldc, sAb, sAh, sBb, sBh, sCb, sCh, nh,
      scale, alpha, beta, flags);
}

extern "C" void kernel_launch(void* const* d_in, const int* in_sizes, int n_in,
                              void* d_out, int out_size, void* d_ws, size_t ws_size,
                              hipStream_t stream)
{
  const int*   xin  = (const int*)d_in[0];
  const float* enc  = (const float*)d_in[1];
  const float* pos  = (const float*)d_in[2];
  const float* ln1s = (const float*)d_in[3];
  const float* ln1b = (const float*)d_in[4];
  const float* qkvw = (const float*)d_in[5];
  const float* ow   = (const float*)d_in[6];
  const float* ob   = (const float*)d_in[7];
  const float* ck   = (const float*)d_in[8];
  const float* ln2s = (const float*)d_in[9];
  const float* ln2b = (const float*)d_in[10];
  const float* w1   = (const float*)d_in[11];
  const float* b1   = (const float*)d_in[12];
  const float* w2   = (const float*)d_in[13];
  const float* b2   = (const float*)d_in[14];
  const float* fw   = (const float*)d_in[15];
  const float* fb   = (const float*)d_in[16];
  float* out = (float*)d_out;

  // ---- workspace layout: 206,831,680 bytes ----
  const size_t NEED = 206831680ULL;
  if (ws_size < NEED) return;

  char* P = (char*)d_ws;
  float* h    = (float*)P; P += 32768000;      // (16,1000,512) f32
  u16*   X16  = (u16*)P;   P += 16777216;      // attn2 probs bf16 (128,256,256)
  char*  R    = P;         P += 83886080;      // time-shared region (see below)
  u16*   qkv  = (u16*)P;   P += 50331648;      // bf16 (16,1024,1536)
  u16*   ql   = (u16*)P;   P += 4194304;       // (bh,256,64)
  u16*   kl   = (u16*)P;   P += 4194304;       // (bh,256,64)
  u16*   a3v  = (u16*)P;   P += 4194304;       // (bh,256,64)
  u16*   Wl   = (u16*)P;   P += 4194304;       // (bh,256,64)
  u16*   qkvwT= (u16*)P;   P += 1572864;       // (1536,512)
  u16*   owT  = (u16*)P;   P += 524288;        // (512,512)
  u16*   w1T  = (u16*)P;   P += 2097152;       // (2048,512)
  u16*   w2T  = (u16*)P;   P += 2097152;       // (512,2048)
  float* scal = (float*)P; P += 64;

  // region R time-sharing:
  //  pre-pinv:  attn2 logits f32 (33.5MB @ R+0) -> attn3 probs bf16 (33.5MB @ R+0)
  //  pinv:      E,F,G,Za,Zb bf16 (5 x 16.8MB)
  //  post-pinv: probs (attn1/FF1) @ R+0, xln @ R+32M, apre @ R+48M
  float* Rf  = (float*)R;                       // attn2 logits f32
  u16*   Em  = (u16*)(R + 0);
  u16*   Fm  = (u16*)(R + 16777216);
  u16*   Gm  = (u16*)(R + 33554432);
  u16*   Za  = (u16*)(R + 50331648);
  u16*   Zb  = (u16*)(R + 67108864);
  u16*   probs = (u16*)(R + 0);                 // 33.5MB
  u16*   xln   = (u16*)(R + 33554432);          // 16.8MB
  u16*   apre  = (u16*)(R + 50331648);          // 16.8MB

  embed_kernel<<<32000, 256, 0, stream>>>(xin, enc, pos, h);

  for (int i = 0; i < DEPTH_; i++){
    // weight transposes (f32 -> bf16 [N][K])
    tconv_kernel<<<dim3(48, 16), 256, 0, stream>>>(qkvw + (long long)i * 786432, qkvwT, 512, 1536);
    tconv_kernel<<<dim3(16, 16), 256, 0, stream>>>(ow + (long long)i * 262144, owT, 512, 512);
    tconv_kernel<<<dim3(64, 16), 256, 0, stream>>>(w1 + (long long)i * 1048576, w1T, 512, 2048);
    tconv_kernel<<<dim3(16, 64), 256, 0, stream>>>(w2 + (long long)i * 1048576, w2T, 2048, 512);

    // LN1 -> padded bf16 xln (16,1024,512)
    ln_kernel<<<16384, 256, 0, stream>>>(h, xln, ln1s + i * 512, ln1b + i * 512, 1);

    // QKV: (16384,512) @ (512,1536) -> qkv bf16
    mg<0,1>(stream, xln, qkvwT, qkv, nullptr, 16384, 1536, 512, 512, 512, 1536,
            0,0, 0,0, 0,0, 1, 1, -1.f, 0.f, 0.f, 0);

    landmark_kernel<<<8192, 256, 0, stream>>>(qkv, ql, kl);

    // attn2 logits f32 -> Rf; softmax -> X16 bf16
    mg<0,0>(stream, ql, kl, Rf, nullptr, 256, 256, 64, 64, 64, 256,
            131072, 16384, 131072, 16384, 524288, 65536, 128, 8, -1.f, 0.f, 0.f, 0);
    softmax_f2b<<<32768, 256, 0, stream>>>(Rf, X16);

    // attn3 (+@v) in 2 bh-chunks of 64 (probs region overlays attn2 logits; done in order)
    for (int c = 0; c < 2; c++){
      mg<0,1>(stream, ql + (long long)c * 64 * 16384, qkv + (long long)c * 8 * 1572864 + 512,
              probs, nullptr, 256, 1024, 64, 64, 1536, 1024,
              131072, 16384, 1572864, 64, 2097152, 262144, 64, 8, -1.f, 0.f, 0.f, 0);
      softmax_bf16<4><<<16384, 256, 0, stream>>>(probs);
      mg<1,1>(stream, probs, qkv + (long long)c * 8 * 1572864 + 1024,
              a3v + (long long)c * 64 * 16384, nullptr, 256, 64, 1024, 1024, 1536, 64,
              2097152, 262144, 1572864, 64, 131072, 16384, 64, 8, -1.f, 0.f, 0.f, 0);
    }

    // pinv scaling factors (global over all bh)
    zero_kernel<<<1, 64, 0, stream>>>(scal, 16);
    rcmax_kernel<<<128, 256, 0, stream>>>(X16, scal);

    // ---- residual-form Newton-Schulz, batch 128, plain bf16 ----
    // Z0 = X^T/c ; E = X@Z - I
    // per iter: F = 5E - E@E ; G = 9E - F - E@F ; Z' = 0.25(4Z - Z@G) ; E = X@Z' - I
    zinit_kernel<<<32768, 256, 0, stream>>>(X16, Za, scal);
    mg<1,1>(stream, X16, Za, Em, nullptr, 256, 256, 256, 256, 256, 256,
            65536, 0, 65536, 0, 65536, 0, 128, 1, -1.f, 0.f, 0.f, 4);
    u16 *Zc = Za, *Zn = Zb;
    for (int it = 0; it < 6; it++){
      mg<1,1>(stream, Em, Em, Fm, nullptr, 256, 256, 256, 256, 256, 256,
              65536, 0, 65536, 0, 65536, 0, 128, 1, 1.f, 5.f, 0.f, 0);
      mg<1,1>(stream, Em, Fm, Gm, nullptr, 256, 256, 256, 256, 256, 256,
              65536, 0, 65536, 0, 65536, 0, 128, 1, 1.f, 9.f, -1.f, 0);
      mg<1,1>(stream, Zc, Gm, Zn, nullptr, 256, 256, 256, 256, 256, 256,
              65536, 0, 65536, 0, 65536, 0, 128, 1, 0.25f, 4.f, 0.f, 0);
      if (it < 5)
        mg<1,1>(stream, X16, Zn, Em, nullptr, 256, 256, 256, 256, 256, 256,
                65536, 0, 65536, 0, 65536, 0, 128, 1, -1.f, 0.f, 0.f, 4);
      u16* tmp = Zc; Zc = Zn; Zn = tmp;
    }
    // Wl = Z_final @ a3v  (Z_final = Zc)
    mg<1,1>(stream, Zc, a3v, Wl, nullptr, 256, 64, 256, 256, 64, 64,
            65536, 0, 16384, 0, 16384, 0, 128, 1, -1.f, 0.f, 0.f, 0);

    // depthwise conv(v) -> apre (bf16, overwrite)
    conv_kernel<<<32768, 256, 0, stream>>>(qkv, ck + i * 264, apre);

    // attn1 (+@Wl accumulate into apre) in 2 b-chunks of 8
    for (int c = 0; c < 2; c++){
      mg<0,1>(stream, qkv + (long long)c * 8 * 1572864, kl + (long long)c * 8 * 131072,
              probs, nullptr, 1024, 256, 64, 1536, 64, 256,
              1572864, 64, 131072, 16384, 2097152, 262144, 64, 8, -SCALE_, 0.f, 0.f, 0);
      softmax_bf16<1><<<65536, 256, 0, stream>>>(probs);
      mg<1,1>(stream, probs, Wl + (long long)c * 64 * 16384,
              apre + (long long)c * 8 * 524288, nullptr, 1024, 64, 256, 256, 64, 512,
              2097152, 262144, 131072, 16384, 524288, 64, 64, 8, -1.f, 0.f, 0.f, 1);
    }

    // h += apre[:, 24:, :] @ out_w + out_b
    mg<0,0>(stream, apre + PAD_ * 512, owT, h, ob + i * 512,
            1000, 512, 512, 512, 512, 512,
            524288, 0, 0, 0, 512000, 0, 16, 1, -1.f, 0.f, 0.f, 1);

    // LN2 -> compact bf16 (16000,512)
    ln_kernel<<<16000, 256, 0, stream>>>(h, xln, ln2s + i * 512, ln2b + i * 512, 0);

    // FF in 2 N-chunks of 1024
    for (int c = 0; c < 2; c++){
      mg<0,1>(stream, xln, w1T + (long long)c * 1024 * 512, probs,
              b1 + i * 2048 + c * 1024, 16000, 1024, 512, 512, 512, 1024,
              0,0, 0,0, 0,0, 1, 1, -1.f, 0.f, 0.f, 2);
      mg<0,0>(stream, probs, w2T + (long long)c * 1024, h,
              (c == 0) ? (b2 + i * 512) : nullptr,
              16000, 512, 1024, 1024, 2048, 512,
              0,0, 0,0, 0,0, 1, 1, -1.f, 0.f, 0.f, 1);
    }
  }

  final_kernel<<<16, 256, 0, stream>>>(h, fw, fb, out);
}

// Round 7
// 11038.848 us; speedup vs baseline: 2.8090x; 1.1613x over previous
//
#include <hip/hip_runtime.h>
#include <hip/hip_bf16.h>
#include <math.h>

typedef unsigned short u16;
typedef unsigned int   u32;
typedef __attribute__((ext_vector_type(8))) short short8;
typedef __attribute__((ext_vector_type(4))) float f32x4;

#define L_ 1000
#define D_ 512
#define N_ 1024
#define DEPTH_ 6
#define PAD_ 24
#define SCALE_ 0.125f

__device__ inline float bf2f(u16 u){ union{u32 i; float f;} x; x.i = ((u32)u) << 16; return x.f; }
__device__ inline u16 f2bf(float f){
  union{float f; u32 i;} x; x.f = f;
  u32 r = x.i + 0x7fffu + ((x.i >> 16) & 1u);
  return (u16)(r >> 16);
}

// ---------- block reductions (256 threads = 4 waves of 64) ----------
__device__ inline float blockSum256(float v, float* red){
  int t = threadIdx.x;
  #pragma unroll
  for (int o = 32; o > 0; o >>= 1) v += __shfl_down(v, o, 64);
  __syncthreads();
  if ((t & 63) == 0) red[t >> 6] = v;
  __syncthreads();
  return red[0] + red[1] + red[2] + red[3];
}
__device__ inline float blockMax256(float v, float* red){
  int t = threadIdx.x;
  #pragma unroll
  for (int o = 32; o > 0; o >>= 1) v = fmaxf(v, __shfl_down(v, o, 64));
  __syncthreads();
  if ((t & 63) == 0) red[t >> 6] = v;
  __syncthreads();
  return fmaxf(fmaxf(red[0], red[1]), fmaxf(red[2], red[3]));
}

// ---------- embedding ----------
__global__ __launch_bounds__(256) void embed_kernel(
    const int* __restrict__ x, const float* __restrict__ ee,
    const float* __restrict__ pe, float* __restrict__ h)
{
  long long i = (long long)blockIdx.x * 256 + threadIdx.x;  // 16*1000*512
  int d = (int)(i & 511);
  long long bl = i >> 9;
  int l = (int)(bl % 1000);
  int tok = x[bl];
  h[i] = ee[tok * D_ + d] + pe[l * D_ + d];
}

// ---------- layernorm: f32 in -> bf16(u16) out ----------
__global__ __launch_bounds__(256) void ln_kernel(
    const float* __restrict__ in, u16* __restrict__ out,
    const float* __restrict__ sc, const float* __restrict__ bi, int pad)
{
  __shared__ float red[4];
  int r = blockIdx.x, t = threadIdx.x;
  const float* row; u16* orow;
  if (pad){
    int bb = r >> 10, n = r & 1023;
    orow = out + (long long)r * D_;
    if (n < PAD_){ orow[t] = 0; orow[t + 256] = 0; return; }
    row = in + ((long long)bb * L_ + (n - PAD_)) * D_;
  } else {
    row  = in  + (long long)r * D_;
    orow = out + (long long)r * D_;
  }
  float x0 = row[t], x1 = row[t + 256];
  float mu = blockSum256(x0 + x1, red) * (1.f / 512.f);
  float d0 = x0 - mu, d1 = x1 - mu;
  float var = blockSum256(d0 * d0 + d1 * d1, red) * (1.f / 512.f);
  float rs = rsqrtf(var + 1e-5f);
  orow[t]       = f2bf(d0 * rs * sc[t]       + bi[t]);
  orow[t + 256] = f2bf(d1 * rs * sc[t + 256] + bi[t + 256]);
}

// ---------- weight transpose+convert: src f32 [K][N] -> dst bf16 [N][K] ----------
__global__ __launch_bounds__(256) void tconv_kernel(
    const float* __restrict__ src, u16* __restrict__ dst, int K, int N)
{
  __shared__ float tile[32][33];
  int kg = blockIdx.y << 5, ng = blockIdx.x << 5;
  int t = threadIdx.x;
  int kr = t >> 3, nc = (t & 7) << 2;
  float4 v = *(const float4*)(src + (long long)(kg + kr) * N + ng + nc);
  tile[kr][nc + 0] = v.x; tile[kr][nc + 1] = v.y;
  tile[kr][nc + 2] = v.z; tile[kr][nc + 3] = v.w;
  __syncthreads();
  int nr = t >> 3, kc = (t & 7) << 2;
  ushort4 o;
  o.x = f2bf(tile[kc + 0][nr]); o.y = f2bf(tile[kc + 1][nr]);
  o.z = f2bf(tile[kc + 2][nr]); o.w = f2bf(tile[kc + 3][nr]);
  *(ushort4*)(dst + (long long)(ng + nr) * K + kg + kc) = o;
}

// ---------- v transpose: vT[bh][d][n] = qkv[b,n,1024 + h*64 + d], LDS-tiled ----
__global__ __launch_bounds__(256) void vtrans_kernel(
    const u16* __restrict__ qkv, u16* __restrict__ vT)
{
  __shared__ u16 tile[32][36];
  int idx = blockIdx.x;                 // 128 bh * 2 dt * 32 nt = 8192
  int bh = idx >> 6, rem = idx & 63;
  int dt = rem >> 5, nt = rem & 31;
  int b = bh >> 3, hh = bh & 7;
  int t = threadIdx.x;
  {
    int nr = t >> 3, dc = (t & 7) << 2;
    const u16* src = qkv + ((long long)b * N_ + nt * 32 + nr) * 1536 + 1024 + hh * 64 + dt * 32 + dc;
    ushort4 v = *(const ushort4*)src;
    tile[nr][dc + 0] = v.x; tile[nr][dc + 1] = v.y;
    tile[nr][dc + 2] = v.z; tile[nr][dc + 3] = v.w;
  }
  __syncthreads();
  {
    int dr = t >> 3, nc = (t & 7) << 2;
    ushort4 o;
    o.x = tile[nc + 0][dr]; o.y = tile[nc + 1][dr];
    o.z = tile[nc + 2][dr]; o.w = tile[nc + 3][dr];
    *(ushort4*)(vT + (long long)bh * 65536 + (dt * 32 + dr) * 1024 + nt * 32 + nc) = o;
  }
}

// =========================================================================
// MFMA GEMM (bf16 x bf16, f32 acc).  B source is ALWAYS [n][k] (transposed
// copy, ldb = n-row stride).
// C = scale*(alpha*A[i,j] + beta*Bt[i,j] - A@B)   (beta reads B[col][row])
// OUT: 0 = f32 C ; 1 = bf16 C.  WC: write C.  TR: also write C^T (bf16).
// flags: 1 = accumulate into C, 2 = exact gelu, 4 = subtract identity
// tile 128x128, BK=32, 256 threads (4 waves, 2x2 of 64x64)
// =========================================================================
template<int OUT, int WC, int TR>
__global__ __launch_bounds__(256) void mgemm(
    const u16* __restrict__ A16, const u16* __restrict__ B16, void* __restrict__ Cv,
    u16* __restrict__ CT, const float* __restrict__ bias,
    int M, int N, int K, int lda, int ldb, int ldc, int ldct,
    long long sAb, long long sAh, long long sBb, long long sBh,
    long long sCb, long long sCh, long long sCT, int nh,
    float scale, float alpha, float beta, int flags)
{
  __shared__ u16 SH[20480];            // As[10240] + Bs[10240]; aliased as T[128][144]
  u16* As = SH;
  u16* Bs = SH + 10240;

  const int t = threadIdx.x;
  const int bz = blockIdx.z;
  const int b = bz / nh, hh = bz - b * nh;
  const int m0 = blockIdx.y << 7, n0 = blockIdx.x << 7;

  const u16* A = A16 + (long long)b * sAb + (long long)hh * sAh;
  const u16* B = B16 + (long long)b * sBb + (long long)hh * sBh;

  f32x4 acc[4][4];
  #pragma unroll
  for (int i = 0; i < 4; i++)
    #pragma unroll
    for (int j = 0; j < 4; j++) acc[i][j] = (f32x4)0.f;

  const int w = t >> 6, lane = t & 63;
  const int wm = (w >> 1) << 6, wn = (w & 1) << 6;
  const int fr = lane & 15, ko = (lane >> 4) << 3;

  for (int k0 = 0; k0 < K; k0 += 32){
    {
      int row = t >> 1, kq = (t & 1) << 4;
      int gr = m0 + row;
      uint4 v0 = make_uint4(0,0,0,0), v1 = make_uint4(0,0,0,0);
      if (gr < M){
        const uint4* p = (const uint4*)(A + (long long)gr * lda + k0 + kq);
        v0 = p[0]; v1 = p[1];
      }
      *(uint4*)(As + row * 40 + kq)     = v0;
      *(uint4*)(As + row * 40 + kq + 8) = v1;
    }
    {
      int nrow = t >> 1, kq = (t & 1) << 4;
      uint4 v0 = make_uint4(0,0,0,0), v1 = make_uint4(0,0,0,0);
      if (n0 + nrow < N){
        const uint4* p = (const uint4*)(B + (long long)(n0 + nrow) * ldb + k0 + kq);
        v0 = p[0]; v1 = p[1];
      }
      *(uint4*)(Bs + nrow * 40 + kq)     = v0;
      *(uint4*)(Bs + nrow * 40 + kq + 8) = v1;
    }
    __syncthreads();

    short8 ah[4], bh_[4];
    #pragma unroll
    for (int i = 0; i < 4; i++) ah[i] = *(const short8*)(As + (wm + i*16 + fr) * 40 + ko);
    #pragma unroll
    for (int j = 0; j < 4; j++) bh_[j] = *(const short8*)(Bs + (wn + j*16 + fr) * 40 + ko);
    #pragma unroll
    for (int i = 0; i < 4; i++)
      #pragma unroll
      for (int j = 0; j < 4; j++)
        acc[i][j] = __builtin_amdgcn_mfma_f32_16x16x32_bf16(ah[i], bh_[j], acc[i][j], 0, 0, 0);
    __syncthreads();
  }

  // ---- epilogue ----
  const long long coff = (long long)b * sCb + (long long)hh * sCh;
  const int quad = (lane >> 4) << 2;
  #pragma unroll
  for (int i = 0; i < 4; i++){
    #pragma unroll
    for (int j = 0; j < 4; j++){
      #pragma unroll
      for (int r = 0; r < 4; r++){
        int row = m0 + wm + i*16 + quad + r;
        int col = n0 + wn + j*16 + fr;
        if (row < M && col < N){
          float v = acc[i][j][r];
          float at = (alpha != 0.f) ? bf2f(A[(long long)row * lda + col]) : 0.f;
          float bt = (beta  != 0.f) ? bf2f(B[(long long)col * ldb + row]) : 0.f;
          v = scale * (alpha * at + beta * bt - v);
          if (flags & 4) v -= (row == col) ? 1.f : 0.f;
          if (bias) v += bias[col];
          if (flags & 2) v = 0.5f * v * (1.f + erff(v * 0.7071067811865476f));
          if constexpr (WC){
            if constexpr (OUT == 0){
              float* cp = (float*)Cv + coff + (long long)row * ldc + col;
              if (flags & 1) v += *cp;
              *cp = v;
            } else {
              u16* cp = (u16*)Cv + coff + (long long)row * ldc + col;
              if (flags & 1) v += bf2f(*cp);
              *cp = f2bf(v);
            }
          }
          if constexpr (TR)
            SH[(wn + j*16 + fr) * 144 + (wm + i*16 + quad + r)] = f2bf(v);
        }
      }
    }
  }
  if constexpr (TR){
    __syncthreads();
    const long long cofft = (long long)bz * sCT;
    #pragma unroll
    for (int c2 = 0; c2 < 8; c2++){
      int idx = c2 * 256 + t;
      int cl = idx >> 4, ms = (idx & 15) << 3;
      int gcol = n0 + cl;
      if (gcol < N && m0 + ms < M){
        uint4 val = *(const uint4*)(SH + cl * 144 + ms);
        *(uint4*)(CT + cofft + (long long)gcol * ldct + m0 + ms) = val;
      }
    }
  }
}

// ---------- bf16 row softmax, row length = PER*256, in place ----------
template<int PER>
__global__ __launch_bounds__(256) void softmax_bf16(u16* __restrict__ d)
{
  __shared__ float red[4];
  long long r = blockIdx.x;
  u16* row = d + r * (PER * 256);
  int t = threadIdx.x;
  float vals[PER];
  float mx = -3.4e38f;
  #pragma unroll
  for (int i = 0; i < PER; i++){ vals[i] = bf2f(row[t + i * 256]); mx = fmaxf(mx, vals[i]); }
  mx = blockMax256(mx, red);
  float s = 0.f;
  #pragma unroll
  for (int i = 0; i < PER; i++){ vals[i] = expf(vals[i] - mx); s += vals[i]; }
  s = blockSum256(s, red);
  float inv = 1.f / s;
  #pragma unroll
  for (int i = 0; i < PER; i++) row[t + i * 256] = f2bf(vals[i] * inv);
}

// ---------- f32 softmax over 256 -> bf16 out (attn2) ----------
__global__ __launch_bounds__(256) void softmax_f2b(
    const float* __restrict__ in, u16* __restrict__ out)
{
  __shared__ float red[4];
  long long r = blockIdx.x;
  const float* row = in + r * 256;
  int t = threadIdx.x;
  float val = row[t];
  float mx = blockMax256(val, red);
  val = expf(val - mx);
  float s = blockSum256(val, red);
  out[r * 256 + t] = f2bf(val / s);
}

// ---------- landmarks: ql (scaled) and kl, both (bh,256,64) bf16 ----------
__global__ __launch_bounds__(256) void landmark_kernel(
    const u16* __restrict__ qkv, u16* __restrict__ ql, u16* __restrict__ kl)
{
  long long i = (long long)blockIdx.x * 256 + threadIdx.x;  // 128*256*64
  int d = (int)(i & 63);
  long long r = i >> 6;
  int m = (int)(r & 255);
  int bh = (int)(r >> 8);
  int hh = bh & 7, b = bh >> 3;
  const u16* base = qkv + ((long long)b * N_ + m * 4) * 1536 + hh * 64 + d;
  float qs = bf2f(base[0]) + bf2f(base[1536]) + bf2f(base[3072]) + bf2f(base[4608]);
  float ks = bf2f(base[512]) + bf2f(base[2048]) + bf2f(base[3584]) + bf2f(base[5120]);
  ql[i] = f2bf(qs * 0.25f * SCALE_);
  kl[i] = f2bf(ks * 0.25f);
}

// ---------- pinv scale helpers ----------
__global__ void zero_kernel(float* p, int n){
  int i = blockIdx.x * 64 + threadIdx.x;
  if (i < n) p[i] = 0.f;
}
// 256 blocks: 0..127 col-sums, 128..255 row-sums
__global__ __launch_bounds__(256) void rcmax_kernel(
    const u16* __restrict__ x, float* __restrict__ scal)
{
  __shared__ float red[4];
  int bid = blockIdx.x, t = threadIdx.x;
  if (bid < 128){
    const u16* X = x + (long long)bid * 65536;
    float cs = 0.f;
    for (int m = 0; m < 256; m++) cs += fabsf(bf2f(X[m * 256 + t]));
    float cmax = blockMax256(cs, red);
    if (t == 0) atomicMax((unsigned int*)(scal + 1), __float_as_uint(cmax));
  } else {
    const u16* X = x + (long long)(bid - 128) * 65536;
    float rs = 0.f;
    for (int j = 0; j < 256; j++) rs += fabsf(bf2f(X[t * 256 + j]));
    float rmax = blockMax256(rs, red);
    if (t == 0) atomicMax((unsigned int*)(scal + 0), __float_as_uint(rmax));
  }
}
// z0 = x^T * inv (scatter) and z0T = x * inv (coalesced); grid 32768
__global__ __launch_bounds__(256) void zinit_kernel(
    const u16* __restrict__ x, u16* __restrict__ z, u16* __restrict__ zt,
    const float* __restrict__ scal)
{
  float inv = 1.f / (scal[0] * scal[1]);
  long long i = (long long)blockIdx.x * 256 + threadIdx.x;  // 128*65536
  long long bh = i >> 16;
  int ij = (int)(i & 65535);
  int ii = ij >> 8, jj = ij & 255;
  z[i]  = f2bf(bf2f(x[(bh << 16) + (jj << 8) + ii]) * inv);
  zt[i] = f2bf(bf2f(x[i]) * inv);
}

// ---------- depthwise conv (k=33), LDS-cached rows, writes apre ----------
__global__ __launch_bounds__(256) void conv_kernel(
    const u16* __restrict__ qkv, const float* __restrict__ ck, u16* __restrict__ out)
{
  __shared__ u16 V[40 * 512];
  int idx = blockIdx.x;                 // 16 b * 128 ngroups
  int b = idx >> 7, n0 = (idx & 127) << 3;
  int t = threadIdx.x;
  #pragma unroll
  for (int i = 0; i < 10; i++){
    int s = t + i * 256;                // uint4 slot: 40 rows * 64
    int row = s >> 6, col8 = (s & 63) << 3;
    int n = n0 - 16 + row;
    uint4 v = make_uint4(0,0,0,0);
    if (n >= 0 && n < N_)
      v = *(const uint4*)(qkv + ((long long)b * N_ + n) * 1536 + 1024 + col8);
    *(uint4*)(V + row * 512 + col8) = v;
  }
  __syncthreads();
  int hh = t >> 5;                      // head of channels (2t, 2t+1)
  float wts[33];
  #pragma unroll
  for (int k = 0; k < 33; k++) wts[k] = ck[hh * 33 + k];
  const u32* Vw = (const u32*)V;
  u32* O = (u32*)out;
  #pragma unroll 2
  for (int nn = 0; nn < 8; nn++){
    float a0 = 0.f, a1 = 0.f;
    #pragma unroll
    for (int k = 0; k < 33; k++){
      u32 pv = Vw[(nn + k) * 256 + t];
      a0 += bf2f((u16)(pv & 0xffffu)) * wts[k];
      a1 += bf2f((u16)(pv >> 16))     * wts[k];
    }
    O[((long long)b * N_ + n0 + nn) * 256 + t] = (u32)f2bf(a0) | ((u32)f2bf(a1) << 16);
  }
}

// ---------- final ----------
__global__ __launch_bounds__(256) void final_kernel(
    const float* __restrict__ h, const float* __restrict__ w,
    const float* __restrict__ bb, float* __restrict__ out)
{
  __shared__ float red[4];
  int b = blockIdx.x, t = threadIdx.x;
  const float* hp = h + (long long)b * (L_ * D_);
  float acc = 0.f;
  for (int i = t; i < L_ * D_; i += 256) acc += hp[i] * w[i];
  acc = blockSum256(acc, red);
  if (t == 0) out[b] = acc + bb[0];
}

// ---------- host wrapper ----------
template<int OUT, int WC, int TR>
static inline void mg(hipStream_t st, const void* A, const void* B, void* C, void* CT,
  const float* bias, int M, int N, int K, int lda, int ldb, int ldc, int ldct,
  long long sAb, long long sAh, long long sBb, long long sBh,
  long long sCb, long long sCh, long long sCT, int batch, int nh,
  float scale, float alpha, float beta, int flags)
{
  dim3 g((N + 127) >> 7, (M + 127) >> 7, batch);
  mgemm<OUT, WC, TR><<<g, 256, 0, st>>>((const u16*)A, (const u16*)B, C, (u16*)CT, bias,
      M, N, K, lda, ldb, ldc, ldct, sAb, sAh, sBb, sBh, sCb, sCh, sCT, nh,
      scale, alpha, beta, flags);
}

extern "C" void kernel_launch(void* const* d_in, const int* in_sizes, int n_in,
                              void* d_out, int out_size, void* d_ws, size_t ws_size,
                              hipStream_t stream)
{
  const int*   xin  = (const int*)d_in[0];
  const float* enc  = (const float*)d_in[1];
  const float* pos  = (const float*)d_in[2];
  const float* ln1s = (const float*)d_in[3];
  const float* ln1b = (const float*)d_in[4];
  const float* qkvw = (const float*)d_in[5];
  const float* ow   = (const float*)d_in[6];
  const float* ob   = (const float*)d_in[7];
  const float* ck   = (const float*)d_in[8];
  const float* ln2s = (const float*)d_in[9];
  const float* ln2b = (const float*)d_in[10];
  const float* w1   = (const float*)d_in[11];
  const float* b1   = (const float*)d_in[12];
  const float* w2   = (const float*)d_in[13];
  const float* b2   = (const float*)d_in[14];
  const float* fw   = (const float*)d_in[15];
  const float* fb   = (const float*)d_in[16];
  float* out = (float*)d_out;

  // ---- workspace: 223,608,896 bytes (<= proven-available ~242 MB) ----
  const size_t NEED = 223608896ULL;
  if (ws_size < NEED) return;

  const long long SL = 16777216;   // 16 MB slot
  char* P = (char*)d_ws;
  float* h    = (float*)P; P += 32768000;   // (16,1000,512) f32
  u16*   X16  = (u16*)P;   P += 16777216;   // attn2 probs bf16 (128,256,256)
  char*  R    = P;         P += 6 * SL;     // 6 time-shared 16MB slots
  u16*   qkv  = (u16*)P;   P += 50331648;   // bf16 (16,1024,1536)
  u16*   ql   = (u16*)P;   P += 4194304;
  u16*   kl   = (u16*)P;   P += 4194304;
  u16*   a3vT = (u16*)P;   P += 4194304;    // (bh,64,256)
  u16*   WlT  = (u16*)P;   P += 4194304;    // (bh,64,256)
  u16*   qkvwT= (u16*)P;   P += 1572864;
  u16*   owT  = (u16*)P;   P += 524288;
  u16*   w1T  = (u16*)P;   P += 2097152;
  u16*   w2T  = (u16*)P;   P += 2097152;
  float* scal = (float*)P; P += 64;

  // R slot aliases
  float* Rf   = (float*)R;                  // attn2 logits f32 (slots 0-1)
  u16* probs3 = (u16*)R;                    // attn3 probs (slots 0-3, 67MB)
  u16* vT     = (u16*)(R + 4*SL);           // v^T (bh,64,1024), pre-pinv
  u16* Em     = (u16*)(R + 0*SL);
  u16* ET     = (u16*)(R + 1*SL);
  u16* Za     = (u16*)(R + 2*SL);
  u16* Zb     = (u16*)(R + 3*SL);
  u16* T1     = (u16*)(R + 4*SL);
  u16* T2     = (u16*)(R + 5*SL);
  u16* probs1 = (u16*)R;                    // attn1 probs (slots 0-3) / FF1 (slots 0-1)
  u16* apre   = (u16*)(R + 4*SL);           // (16,1024,512)
  u16* xln    = (u16*)(R + 5*SL);           // LN out

  embed_kernel<<<32000, 256, 0, stream>>>(xin, enc, pos, h);

  for (int i = 0; i < DEPTH_; i++){
    tconv_kernel<<<dim3(48, 16), 256, 0, stream>>>(qkvw + (long long)i * 786432, qkvwT, 512, 1536);
    tconv_kernel<<<dim3(16, 16), 256, 0, stream>>>(ow + (long long)i * 262144, owT, 512, 512);
    tconv_kernel<<<dim3(64, 16), 256, 0, stream>>>(w1 + (long long)i * 1048576, w1T, 512, 2048);
    tconv_kernel<<<dim3(16, 64), 256, 0, stream>>>(w2 + (long long)i * 1048576, w2T, 2048, 512);

    // LN1 -> padded bf16 xln
    ln_kernel<<<16384, 256, 0, stream>>>(h, xln, ln1s + i * 512, ln1b + i * 512, 1);

    // QKV
    mg<1,1,0>(stream, xln, qkvwT, qkv, nullptr, nullptr, 16384, 1536, 512, 512, 512, 1536, 0,
              0,0, 0,0, 0,0, 0, 1, 1, -1.f, 0.f, 0.f, 0);

    landmark_kernel<<<8192, 256, 0, stream>>>(qkv, ql, kl);
    vtrans_kernel<<<8192, 256, 0, stream>>>(qkv, vT);

    // attn2 logits f32 -> softmax -> X16 bf16
    mg<0,1,0>(stream, ql, kl, Rf, nullptr, nullptr, 256, 256, 64, 64, 64, 256, 0,
              131072, 16384, 131072, 16384, 524288, 65536, 0, 128, 8, -1.f, 0.f, 0.f, 0);
    softmax_f2b<<<32768, 256, 0, stream>>>(Rf, X16);

    // attn3 probs (full batch) -> softmax -> a3vT = (probs @ v)^T
    mg<1,1,0>(stream, ql, qkv + 512, probs3, nullptr, nullptr, 256, 1024, 64, 64, 1536, 1024, 0,
              131072, 16384, 1572864, 64, 2097152, 262144, 0, 128, 8, -1.f, 0.f, 0.f, 0);
    softmax_bf16<4><<<32768, 256, 0, stream>>>(probs3);
    mg<1,0,1>(stream, probs3, vT, nullptr, a3vT, nullptr, 256, 64, 1024, 1024, 1024, 0, 256,
              2097152, 262144, 524288, 65536, 0, 0, 16384, 128, 8, -1.f, 0.f, 0.f, 0);

    // pinv scaling
    zero_kernel<<<1, 64, 0, stream>>>(scal, 16);
    rcmax_kernel<<<256, 256, 0, stream>>>(X16, scal);

    // residual-form Newton-Schulz, batch 128 (all BT=0 via transposed copies)
    zinit_kernel<<<32768, 256, 0, stream>>>(X16, Za, T1, scal);
    // E = X@Z0 - I  (B = Z0^T = T1) -> E + ET
    mg<1,1,1>(stream, X16, T1, Em, ET, nullptr, 256, 256, 256, 256, 256, 256, 256,
              65536, 0, 65536, 0, 65536, 0, 65536, 128, 1, -1.f, 0.f, 0.f, 4);
    u16 *Zc = Za, *Zn = Zb;
    for (int it = 0; it < 6; it++){
      // F = 5E - E@E -> FT (T1)
      mg<1,0,1>(stream, Em, ET, nullptr, T1, nullptr, 256, 256, 256, 256, 256, 0, 256,
                65536, 0, 65536, 0, 0, 0, 65536, 128, 1, 1.f, 5.f, 0.f, 0);
      // G = 9E - F - E@F  (B = FT, beta reads F via FT) -> GT (T2)
      mg<1,0,1>(stream, Em, T1, nullptr, T2, nullptr, 256, 256, 256, 256, 256, 0, 256,
                65536, 0, 65536, 0, 0, 0, 65536, 128, 1, 1.f, 9.f, -1.f, 0);
      // Z' = 0.25(4Z - Z@G)  (B = GT) -> Zn + ZnT (T1)
      mg<1,1,1>(stream, Zc, T2, Zn, T1, nullptr, 256, 256, 256, 256, 256, 256, 256,
                65536, 0, 65536, 0, 65536, 0, 65536, 128, 1, 0.25f, 4.f, 0.f, 0);
      // E = X@Z' - I  (B = ZnT) -> E + ET
      if (it < 5)
        mg<1,1,1>(stream, X16, T1, Em, ET, nullptr, 256, 256, 256, 256, 256, 256, 256,
                  65536, 0, 65536, 0, 65536, 0, 65536, 128, 1, -1.f, 0.f, 0.f, 4);
      u16* tmp = Zc; Zc = Zn; Zn = tmp;
    }
    // WlT = (Z_final @ a3v)^T  (B = a3vT)
    mg<1,0,1>(stream, Zc, a3vT, nullptr, WlT, nullptr, 256, 64, 256, 256, 256, 0, 256,
              65536, 0, 16384, 0, 0, 0, 16384, 128, 1, -1.f, 0.f, 0.f, 0);

    // depthwise conv(v) -> apre
    conv_kernel<<<2048, 256, 0, stream>>>(qkv, ck + i * 264, apre);

    // attn1 probs (full batch) -> softmax -> apre += probs @ Wl (B = WlT)
    mg<1,1,0>(stream, qkv, kl, probs1, nullptr, nullptr, 1024, 256, 64, 1536, 64, 256, 0,
              1572864, 64, 131072, 16384, 2097152, 262144, 0, 128, 8, -SCALE_, 0.f, 0.f, 0);
    softmax_bf16<1><<<131072, 256, 0, stream>>>(probs1);
    mg<1,1,0>(stream, probs1, WlT, apre, nullptr, nullptr, 1024, 64, 256, 256, 256, 512, 0,
              2097152, 262144, 131072, 16384, 524288, 64, 0, 128, 8, -1.f, 0.f, 0.f, 1);

    // h += apre[:, 24:, :] @ out_w + out_b
    mg<0,1,0>(stream, apre + PAD_ * 512, owT, h, nullptr, ob + i * 512,
              1000, 512, 512, 512, 512, 512, 0,
              524288, 0, 0, 0, 512000, 0, 0, 16, 1, -1.f, 0.f, 0.f, 1);

    // LN2 -> compact bf16
    ln_kernel<<<16000, 256, 0, stream>>>(h, xln, ln2s + i * 512, ln2b + i * 512, 0);

    // FF in 2 N-chunks of 1024
    for (int c = 0; c < 2; c++){
      mg<1,1,0>(stream, xln, w1T + (long long)c * 1024 * 512, probs1, nullptr,
                b1 + i * 2048 + c * 1024, 16000, 1024, 512, 512, 512, 1024, 0,
                0,0, 0,0, 0,0, 0, 1, 1, -1.f, 0.f, 0.f, 2);
      mg<0,1,0>(stream, probs1, w2T + (long long)c * 1024, h, nullptr,
                (c == 0) ? (b2 + i * 512) : nullptr,
                16000, 512, 1024, 1024, 2048, 512, 0,
                0,0, 0,0, 0,0, 0, 1, 1, -1.f, 0.f, 0.f, 1);
    }
  }

  final_kernel<<<16, 256, 0, stream>>>(h, fw, fb, out);
}